// Round 11
// baseline (290.671 us; speedup 1.0000x reference)
//
#include <hip/hip_runtime.h>
#include <hip/hip_bf16.h>

// ---------------------------------------------------------------------------
// GCN: 5 layers of  h = relu( norm_dst * scatter_add( (h@W * norm_src)[src] ) + b )
// R11: fuse agg_l + gemm_{l+1}. gemm row r consumes only h row r, so a
// 64-node block aggregates its rows into LDS (stride DIN+4) then runs the
// MFMA gemm in place -> hbuf global round-trip (~110MB) and 4 launches gone.
// tq/qscale ping-pong (A/B) so concurrent blocks never read what another
// block's gemm phase writes. 8 launches total.
// ---------------------------------------------------------------------------

#define THREADS 256
#define HIST_B 256          // edge chunks; hist uses 2*HIST_B blocks
#define HWORDS 12500        // u32 words, 4 nodes/word (8-bit counts), N=50000
#define RS_BLOCKS 196       // ceil(HWORDS/64)
#define G1BLKS 1564         // 2 * ceil(50000/64): gemm1 column-half blocks

typedef __attribute__((ext_vector_type(8))) short short8_t;
typedef __attribute__((ext_vector_type(4))) float float4_t;

__device__ __forceinline__ unsigned short f2bf_rne(float f) {
    unsigned u = __builtin_bit_cast(unsigned, f);
    unsigned r = u + 0x7fffu + ((u >> 16) & 1u);
    return (unsigned short)(r >> 16);
}
__device__ __forceinline__ float bf2f(unsigned short h) {
    return __builtin_bit_cast(float, ((unsigned)h) << 16);
}

// ---------------------------------------------------------------------------
// Split-bf16 MFMA quant epilogue helper (D: col=lane&15, row=quad*4+reg).
// ---------------------------------------------------------------------------
template<int NT, bool NORM>
__device__ __forceinline__ void quant_epilogue(float4_t* acc, const float* __restrict__ norm,
                                               short* __restrict__ outq, float* __restrict__ qscale,
                                               int M, int blk, int tid,
                                               int ostride, int ocol0, int qstride, int qoff) {
    const int w    = tid >> 6;
    const int lane = tid & 63;
    const int ln   = lane & 15;
    const int quad = lane >> 4;
    const int orow = blk * 64 + w * 16 + quad * 4;
#pragma unroll
    for (int i = 0; i < 4; ++i) {
        int r = orow + i;
        float m = 0.f;
#pragma unroll
        for (int nt = 0; nt < NT; ++nt) m = fmaxf(m, fabsf(acc[nt][i]));
#pragma unroll
        for (int off = 1; off < 16; off <<= 1) m = fmaxf(m, __shfl_xor(m, off));
        float s = 1.f;
        if (NORM) s = (r < M) ? norm[r] : 0.f;
        float rowmax = m * s;
        float inv = (rowmax > 0.f) ? (32767.f / rowmax) : 0.f;
        if (r < M) {
            if (ln == 0) qscale[r * qstride + qoff] = rowmax * (1.f / 32767.f);
#pragma unroll
            for (int nt = 0; nt < NT; ++nt)
                outq[(size_t)r * ostride + ocol0 + nt * 16 + ln] =
                    (short)(int)__builtin_rintf(acc[nt][i] * s * inv);
        }
    }
}

// MFMA core, A from global (row-major, width K). Layouts verified m89/m120.
template<int K, int NOUT, bool NORM>
__device__ __forceinline__ void gemm_core(const float* __restrict__ A,
                                          const short* lh, const short* ll,
                                          const float* __restrict__ norm,
                                          short* __restrict__ outq, float* __restrict__ qscale,
                                          int M, int blk, int tid,
                                          int ostride, int ocol0, int qstride, int qoff) {
    constexpr int Kp  = (K + 31) & ~31;
    constexpr int STR = Kp + 8;
    constexpr int NT  = NOUT / 16;
    const int w    = tid >> 6;
    const int lane = tid & 63;
    const int ln   = lane & 15;
    const int quad = lane >> 4;
    const int row  = blk * 64 + w * 16 + ln;
    const bool rv  = row < M;

    float4_t acc[NT];
#pragma unroll
    for (int i = 0; i < NT; ++i) acc[i] = (float4_t){0.f, 0.f, 0.f, 0.f};

#pragma unroll
    for (int kt = 0; kt < Kp / 32; ++kt) {
        const int k0 = kt * 32 + quad * 8;
        float a[8];
        if (rv && k0 < K) {
            float4 v0 = *(const float4*)&A[(size_t)row * K + k0];
            float4 v1 = *(const float4*)&A[(size_t)row * K + k0 + 4];
            a[0] = v0.x; a[1] = v0.y; a[2] = v0.z; a[3] = v0.w;
            a[4] = v1.x; a[5] = v1.y; a[6] = v1.z; a[7] = v1.w;
        } else {
#pragma unroll
            for (int j = 0; j < 8; ++j) a[j] = 0.f;
        }
        short8_t ahi, alo;
#pragma unroll
        for (int j = 0; j < 8; ++j) {
            unsigned short h = f2bf_rne(a[j]);
            ahi[j] = (short)h;
            alo[j] = (short)f2bf_rne(a[j] - bf2f(h));
        }
#pragma unroll
        for (int nt = 0; nt < NT; ++nt) {
            const int bidx = (nt * 16 + ln) * STR + kt * 32 + quad * 8;
            short8_t bh = *(const short8_t*)&lh[bidx];
            short8_t bl = *(const short8_t*)&ll[bidx];
            acc[nt] = __builtin_amdgcn_mfma_f32_16x16x32_bf16(ahi, bh, acc[nt], 0, 0, 0);
            acc[nt] = __builtin_amdgcn_mfma_f32_16x16x32_bf16(ahi, bl, acc[nt], 0, 0, 0);
            acc[nt] = __builtin_amdgcn_mfma_f32_16x16x32_bf16(alo, bh, acc[nt], 0, 0, 0);
        }
    }
    quant_epilogue<NT, NORM>(acc, norm, outq, qscale, M, blk, tid, ostride, ocol0, qstride, qoff);
}

// MFMA core, A from LDS (stride DINP floats, 64 local rows).
template<int K, int NOUT, int DINP>
__device__ __forceinline__ void gemm_core_lds(const float* As,
                                              const short* lh, const short* ll,
                                              const float* __restrict__ norm,
                                              short* __restrict__ outq, float* __restrict__ qscale,
                                              int M, int blk, int tid) {
    constexpr int Kp  = (K + 31) & ~31;
    constexpr int STR = Kp + 8;
    constexpr int NT  = NOUT / 16;
    const int w    = tid >> 6;
    const int lane = tid & 63;
    const int ln   = lane & 15;
    const int quad = lane >> 4;
    const int rloc = w * 16 + ln;
    const bool rv  = (blk * 64 + rloc) < M;

    float4_t acc[NT];
#pragma unroll
    for (int i = 0; i < NT; ++i) acc[i] = (float4_t){0.f, 0.f, 0.f, 0.f};

#pragma unroll
    for (int kt = 0; kt < Kp / 32; ++kt) {
        const int k0 = kt * 32 + quad * 8;
        float a[8];
        if (rv && k0 < K) {
            float4 v0 = *(const float4*)&As[rloc * DINP + k0];
            float4 v1 = *(const float4*)&As[rloc * DINP + k0 + 4];
            a[0] = v0.x; a[1] = v0.y; a[2] = v0.z; a[3] = v0.w;
            a[4] = v1.x; a[5] = v1.y; a[6] = v1.z; a[7] = v1.w;
        } else {
#pragma unroll
            for (int j = 0; j < 8; ++j) a[j] = 0.f;
        }
        short8_t ahi, alo;
#pragma unroll
        for (int j = 0; j < 8; ++j) {
            unsigned short h = f2bf_rne(a[j]);
            ahi[j] = (short)h;
            alo[j] = (short)f2bf_rne(a[j] - bf2f(h));
        }
#pragma unroll
        for (int nt = 0; nt < NT; ++nt) {
            const int bidx = (nt * 16 + ln) * STR + kt * 32 + quad * 8;
            short8_t bh = *(const short8_t*)&lh[bidx];
            short8_t bl = *(const short8_t*)&ll[bidx];
            acc[nt] = __builtin_amdgcn_mfma_f32_16x16x32_bf16(ahi, bh, acc[nt], 0, 0, 0);
            acc[nt] = __builtin_amdgcn_mfma_f32_16x16x32_bf16(ahi, bl, acc[nt], 0, 0, 0);
            acc[nt] = __builtin_amdgcn_mfma_f32_16x16x32_bf16(alo, bh, acc[nt], 0, 0, 0);
        }
    }
    quant_epilogue<NT, true>(acc, norm, outq, qscale, M, blk, tid, NOUT, 0, 1, 0);
}

// W pre-split element: W (KxNOUT fp32) -> W^T hi/lo bf16 [NOUT][STR shorts].
__device__ __forceinline__ void conv_one(const float* __restrict__ W, short* __restrict__ hi,
                                         short* __restrict__ lo, int K, int NOUT, int STR, int i) {
    int n = i / STR;
    int kk = i % STR;
    float v = (kk < K) ? W[(size_t)kk * NOUT + n] : 0.f;
    unsigned short h = f2bf_rne(v);
    hi[i] = (short)h;
    lo[i] = (short)f2bf_rne(v - bf2f(h));
}

// ---------------------------------------------------------------------------
// packed0: gemm1 column-halves (raw quant, per-half scales) || hist || W2-5
// split + flag zeroing. Static LDS 50,048 B -> 3 blocks/CU.
// ---------------------------------------------------------------------------
__global__ __launch_bounds__(THREADS)
void packed0_kernel(const float* __restrict__ x, const float* __restrict__ W1,
                    const float* __restrict__ W2, const float* __restrict__ W3,
                    const float* __restrict__ W4, const float* __restrict__ W5,
                    short* __restrict__ tq, float* __restrict__ qscale2,
                    const int* __restrict__ src, const int* __restrict__ dst,
                    unsigned* __restrict__ p_src, unsigned* __restrict__ p_dst,
                    unsigned char* __restrict__ rank, int* __restrict__ flags,
                    short* w2h, short* w2l, short* w3h, short* w3l,
                    short* w4h, short* w4l, short* w5h, short* w5l,
                    int E, int chunk, int N) {
    __shared__ __align__(16) char smem[50048];
    const int blk = blockIdx.x;
    const int t = threadIdx.x;

    if (blk < G1BLKS) {
        const int h  = blk & 1;
        const int gb = blk >> 1;
        short* lh = (short*)smem;           // 64*136 = 8704 shorts
        short* ll = (short*)smem + 8704;
        for (int j = t; j < 128 * 64; j += THREADS) {
            int kk = j >> 6, n = j & 63;
            float v = W1[kk * 128 + h * 64 + n];
            unsigned short hh = f2bf_rne(v);
            lh[n * 136 + kk] = (short)hh;
            ll[n * 136 + kk] = (short)f2bf_rne(v - bf2f(hh));
        }
        __syncthreads();
        gemm_core<128, 64, false>(x, lh, ll, nullptr, tq, qscale2, N, gb, t,
                                  128, h * 64, 2, h);
    } else if (blk < G1BLKS + 2 * HIST_B) {
        unsigned* bins = (unsigned*)smem;   // 50 KB
        const int hb = blk - G1BLKS;
        const bool is_dst = hb < HIST_B;
        const int b = is_dst ? hb : hb - HIST_B;
        const int e0 = b * chunk;
        int e1 = e0 + chunk; if (e1 > E) e1 = E;
        const int* __restrict__ idx = is_dst ? dst : src;
        unsigned* __restrict__ pout = is_dst ? p_dst : p_src;

        for (int w = t; w < HWORDS; w += THREADS) bins[w] = 0;
        __syncthreads();
        for (int e = e0 + t; e < e1; e += THREADS) {
            int d = idx[e];
            unsigned sh = (unsigned)(d & 3) * 8u;
            unsigned old = atomicAdd(&bins[d >> 2], 1u << sh);
            if (is_dst) rank[e] = (unsigned char)((old >> sh) & 0xffu);
        }
        __syncthreads();
        for (int w = t; w < HWORDS; w += THREADS)
            pout[(size_t)b * HWORDS + w] = bins[w];
    } else {
        int cb = blk - G1BLKS - 2 * HIST_B;     // 0..48
        if (cb == 48) {
            flags[t] = 0;
            return;
        }
        int i = cb * THREADS + t;
        if (i < 8704)                        conv_one(W2, w2h, w2l, 128, 64, 136, i);
        else if ((i -= 8704) < 2304)         conv_one(W3, w3h, w3l, 64, 32, 72, i);
        else if ((i -= 2304) < 640)          conv_one(W4, w4h, w4l, 32, 16, 40, i);
        else { i -= 640;                     conv_one(W5, w5h, w5l, 16, 16, 40, i); }
    }
}

// ---------------------------------------------------------------------------
// reduce_scan: 196 blocks, 64 words/block, 4 chunk-quarters/word; lookback.
// ---------------------------------------------------------------------------
__global__ __launch_bounds__(THREADS)
void reduce_scan_kernel(const unsigned* __restrict__ p_src, unsigned* __restrict__ p_dst,
                        float* __restrict__ norm_src, float* __restrict__ norm_dst,
                        float* __restrict__ qscale2, int* __restrict__ row_ptr,
                        int* __restrict__ flags, int N) {
    __shared__ unsigned qd[4][64];
    __shared__ unsigned qs[4][64];
    __shared__ int sscan[64];
    __shared__ int bexcl_sh;
    const int t  = threadIdx.x;
    const int b  = blockIdx.x;
    const int q  = t >> 6;
    const int wl = t & 63;
    const int w  = b * 64 + wl;
    const bool wv = (w < HWORDS);

    unsigned vals[64];
    unsigned dsum = 0, ssum = 0;
    if (wv) {
#pragma unroll
        for (int i = 0; i < 64; ++i) {
            int c = q * 64 + i;
            vals[i] = p_dst[(size_t)c * HWORDS + w];
            dsum += vals[i];
        }
#pragma unroll
        for (int i = 0; i < 64; ++i) {
            int c = q * 64 + i;
            ssum += p_src[(size_t)c * HWORDS + w];
        }
    }
    qd[q][wl] = dsum;
    qs[q][wl] = ssum;
    __syncthreads();

    unsigned off = 0, dfull = 0, sfull = 0;
#pragma unroll
    for (int qq = 0; qq < 4; ++qq) {
        unsigned v = qd[qq][wl];
        if (qq < q) off += v;
        dfull += v;
        sfull += qs[qq][wl];
    }

    if (wv) {
        unsigned run = off;
#pragma unroll
        for (int i = 0; i < 64; ++i) {
            int c = q * 64 + i;
            p_dst[(size_t)c * HWORDS + w] = run;
            run += vals[i];
        }
    }

    int d0 = 0, d1 = 0, d2 = 0, d3 = 0, wdeg = 0;
    if (q == 0) {
        d0 = (int)(dfull & 0xffu); d1 = (int)((dfull >> 8) & 0xffu);
        d2 = (int)((dfull >> 16) & 0xffu); d3 = (int)(dfull >> 24);
        wdeg = d0 + d1 + d2 + d3;
        if (wv) {
#pragma unroll
            for (int l = 0; l < 4; ++l) {
                int node = 4 * w + l;
                int dd = (l == 0) ? d0 : (l == 1) ? d1 : (l == 2) ? d2 : d3;
                int ds = (int)((sfull >> (8 * l)) & 0xffu);
                norm_dst[node] = rsqrtf((float)(dd < 1 ? 1 : dd));
                float ns = rsqrtf((float)(ds < 1 ? 1 : ds));
                norm_src[node] = ns;
                qscale2[2 * node]     *= ns;
                qscale2[2 * node + 1] *= ns;
            }
        }
        sscan[wl] = wv ? wdeg : 0;
    }
    __syncthreads();
    for (int o = 1; o < 64; o <<= 1) {
        int u = 0;
        if (t < 64 && t >= o) u = sscan[t - o];
        __syncthreads();
        if (t < 64) sscan[t] += u;
        __syncthreads();
    }
    const int btotal = sscan[63];

    if (t == 0) atomicExch(&flags[b], btotal + 1);
    if (t < 64) {
        int v = 0;
        for (int p = t; p < b; p += 64) {
            int f;
            do { f = atomicAdd(&flags[p], 0); } while (f == 0);
            v += f - 1;
        }
#pragma unroll
        for (int o = 1; o < 64; o <<= 1) v += __shfl_xor(v, o);
        if (t == 0) bexcl_sh = v;
    }
    __syncthreads();

    if (q == 0 && wv) {
        int pre = bexcl_sh + sscan[wl] - wdeg;
        int n0 = 4 * w;
        row_ptr[n0 + 0] = pre; pre += d0;
        row_ptr[n0 + 1] = pre; pre += d1;
        row_ptr[n0 + 2] = pre; pre += d2;
        row_ptr[n0 + 3] = pre;
    }
    if (b == RS_BLOCKS - 1 && t == 0) row_ptr[N] = bexcl_sh + btotal;
}

// ---------------------------------------------------------------------------
// scatter: 512 half-chunk blocks, precomputed rank bytes.
// ---------------------------------------------------------------------------
__global__ __launch_bounds__(THREADS)
void scatter_kernel(const int* __restrict__ src, const int* __restrict__ dst,
                    const unsigned char* __restrict__ rank,
                    const int* __restrict__ row_ptr, const unsigned* __restrict__ p_dst,
                    int* __restrict__ col, int E, int chunk) {
    const int bc = blockIdx.x >> 1;
    const int hch = (chunk + 1) >> 1;
    const int e0 = bc * chunk;
    int e1 = e0 + chunk; if (e1 > E) e1 = E;
    int s = e0 + (blockIdx.x & 1) * hch;
    int send = s + hch; if (send > e1) send = e1;
    for (int e = s + threadIdx.x; e < send; e += THREADS) {
        int d = dst[e];
        unsigned sh = (unsigned)(d & 3) * 8u;
        unsigned pre = (p_dst[(size_t)bc * HWORDS + (d >> 2)] >> sh) & 0xffu;
        col[row_ptr[d] + (int)pre + (int)rank[e]] = src[e];
    }
}

// ---------------------------------------------------------------------------
// Fused agg_l + gemm_{l+1}: block aggregates its 64 nodes into LDS (stride
// DIN+4), applies relu+bias+norm_dst, then runs the next layer's MFMA gemm
// from LDS. QS2_IN: layer-1 per-half scales (qs_in[2*s + (col>=64)]).
// ---------------------------------------------------------------------------
template<int DIN, int NOUT, bool QS2_IN>
__global__ __launch_bounds__(THREADS)
void fused_agg_gemm_kernel(const short* __restrict__ tq_in, const float* __restrict__ qs_in,
                           const int* __restrict__ row_ptr, const int* __restrict__ col,
                           const float* __restrict__ norm_dst, const float* __restrict__ bias,
                           const short* __restrict__ wt_hi, const short* __restrict__ wt_lo,
                           const float* __restrict__ norm_src,
                           short* __restrict__ tq_out, float* __restrict__ qs_out, int N) {
    constexpr int Kp   = (DIN + 31) & ~31;
    constexpr int STR  = Kp + 8;
    constexpr int DINP = DIN + 4;
    constexpr int TPN  = DIN / 8;

    __shared__ float As[64 * DINP];
    __shared__ short lh[NOUT * STR];
    __shared__ short ll[NOUT * STR];

    const int tid = threadIdx.x;
    // stage W^T hi/lo
    {
        constexpr int CNT = NOUT * STR / 2;
        const int* gh = (const int*)wt_hi;
        const int* gl = (const int*)wt_lo;
        int* sh = (int*)lh;
        int* sl = (int*)ll;
        for (int i = tid; i < CNT; i += THREADS) { sh[i] = gh[i]; sl[i] = gl[i]; }
    }

    // agg phase -> As
    const int ln = tid % TPN;
    const int half = QS2_IN ? (ln >> 3) : 0;
    for (int n0 = tid / TPN; n0 < 64; n0 += THREADS / TPN) {
        const int node = blockIdx.x * 64 + n0;
        if (node < N) {
            const int beg = row_ptr[node];
            const int end = row_ptr[node + 1];
            float acc[8];
#pragma unroll
            for (int c = 0; c < 8; ++c) acc[c] = 0.f;
            auto scl = [&](int s) -> float { return QS2_IN ? qs_in[2 * s + half] : qs_in[s]; };
            int j = beg;
            for (; j + 3 < end; j += 4) {
                int s0 = col[j], s1 = col[j + 1], s2 = col[j + 2], s3 = col[j + 3];
                short8_t v0 = *(const short8_t*)&tq_in[(size_t)s0 * DIN + ln * 8];
                short8_t v1 = *(const short8_t*)&tq_in[(size_t)s1 * DIN + ln * 8];
                short8_t v2 = *(const short8_t*)&tq_in[(size_t)s2 * DIN + ln * 8];
                short8_t v3 = *(const short8_t*)&tq_in[(size_t)s3 * DIN + ln * 8];
                float c0 = scl(s0), c1 = scl(s1), c2 = scl(s2), c3 = scl(s3);
#pragma unroll
                for (int c = 0; c < 8; ++c)
                    acc[c] += (float)v0[c] * c0 + (float)v1[c] * c1
                            + (float)v2[c] * c2 + (float)v3[c] * c3;
            }
            for (; j < end; ++j) {
                int s0 = col[j];
                short8_t v0 = *(const short8_t*)&tq_in[(size_t)s0 * DIN + ln * 8];
                float c0 = scl(s0);
#pragma unroll
                for (int c = 0; c < 8; ++c) acc[c] += (float)v0[c] * c0;
            }
            float nd = norm_dst[node];
#pragma unroll
            for (int c = 0; c < 8; ++c)
                As[n0 * DINP + ln * 8 + c] = fmaxf(acc[c] * nd + bias[ln * 8 + c], 0.f);
        }
    }
    __syncthreads();

    // gemm phase (A from LDS), int16 quant out
    gemm_core_lds<DIN, NOUT, DINP>(As, lh, ll, norm_src, tq_out, qs_out, N, blockIdx.x, tid);
}

// ---------------------------------------------------------------------------
// Final int16 CSR aggregate (layer 5 output -> d_out).
// ---------------------------------------------------------------------------
template<int D>
__global__ __launch_bounds__(THREADS)
void agg_q_kernel(const short* __restrict__ tq, const float* __restrict__ qscale,
                  const int* __restrict__ row_ptr, const int* __restrict__ col,
                  const float* __restrict__ norm_dst, const float* __restrict__ bias,
                  float* __restrict__ out, int N) {
    constexpr int TPN = D / 8;
    constexpr int NPB = THREADS / TPN;
    const int tid  = threadIdx.x;
    const int ln   = tid % TPN;
    const int g    = tid / TPN;
    const int node = blockIdx.x * NPB + g;
    if (node >= N) return;

    const int beg = row_ptr[node];
    const int end = row_ptr[node + 1];

    float acc[8];
#pragma unroll
    for (int c = 0; c < 8; ++c) acc[c] = 0.f;

    int j = beg;
    for (; j + 3 < end; j += 4) {
        int s0 = col[j], s1 = col[j + 1], s2 = col[j + 2], s3 = col[j + 3];
        short8_t v0 = *(const short8_t*)&tq[(size_t)s0 * D + ln * 8];
        short8_t v1 = *(const short8_t*)&tq[(size_t)s1 * D + ln * 8];
        short8_t v2 = *(const short8_t*)&tq[(size_t)s2 * D + ln * 8];
        short8_t v3 = *(const short8_t*)&tq[(size_t)s3 * D + ln * 8];
        float c0 = qscale[s0], c1 = qscale[s1], c2 = qscale[s2], c3 = qscale[s3];
#pragma unroll
        for (int c = 0; c < 8; ++c)
            acc[c] += (float)v0[c] * c0 + (float)v1[c] * c1
                    + (float)v2[c] * c2 + (float)v3[c] * c3;
    }
    for (; j < end; ++j) {
        int s0 = col[j];
        short8_t v0 = *(const short8_t*)&tq[(size_t)s0 * D + ln * 8];
        float c0 = qscale[s0];
#pragma unroll
        for (int c = 0; c < 8; ++c) acc[c] += (float)v0[c] * c0;
    }

    float nd = norm_dst[node];
    float4 b0 = *(const float4*)&bias[ln * 8];
    float4 b1 = *(const float4*)&bias[ln * 8 + 4];
    float4 o0, o1;
    o0.x = fmaxf(acc[0] * nd + b0.x, 0.f);
    o0.y = fmaxf(acc[1] * nd + b0.y, 0.f);
    o0.z = fmaxf(acc[2] * nd + b0.z, 0.f);
    o0.w = fmaxf(acc[3] * nd + b0.w, 0.f);
    o1.x = fmaxf(acc[4] * nd + b1.x, 0.f);
    o1.y = fmaxf(acc[5] * nd + b1.y, 0.f);
    o1.z = fmaxf(acc[6] * nd + b1.z, 0.f);
    o1.w = fmaxf(acc[7] * nd + b1.w, 0.f);
    *(float4*)&out[(size_t)node * D + ln * 8] = o0;
    *(float4*)&out[(size_t)node * D + ln * 8 + 4] = o1;
}

extern "C" void kernel_launch(void* const* d_in, const int* in_sizes, int n_in,
                              void* d_out, int out_size, void* d_ws, size_t ws_size,
                              hipStream_t stream) {
    const float* x     = (const float*)d_in[0];
    const int*   edges = (const int*)d_in[1];
    const float* W1 = (const float*)d_in[2];  const float* b1 = (const float*)d_in[3];
    const float* W2 = (const float*)d_in[4];  const float* b2 = (const float*)d_in[5];
    const float* W3 = (const float*)d_in[6];  const float* b3 = (const float*)d_in[7];
    const float* W4 = (const float*)d_in[8];  const float* b4 = (const float*)d_in[9];
    const float* W5 = (const float*)d_in[10]; const float* b5 = (const float*)d_in[11];

    const int N = in_sizes[0] / 128;   // 50000
    const int E = in_sizes[1] / 2;     // 800000
    const int* src = edges;
    const int* dst = edges + E;

    // ---- carve workspace ----
    char* ws = (char*)d_ws;
    size_t off = 0;
    auto carve = [&](size_t bytes) -> void* {
        void* p = ws + off;
        off += (bytes + 255) & ~(size_t)255;
        return p;
    };
    short* tqA      = (short*)carve((size_t)N * 128 * 2);   // layers 1,3,5 output
    short* tqB      = (short*)carve((size_t)N * 64 * 2);    // layers 2,4 output
    float* norm_src = (float*)carve((size_t)N * 4);
    float* norm_dst = (float*)carve((size_t)N * 4);
    int*   row_ptr  = (int*)carve((size_t)(N + 1) * 4);
    int*   col      = (int*)carve((size_t)E * 4);
    float* qsA      = (float*)carve((size_t)2 * N * 4);     // L1 per-half; L3/L5 stride-1
    float* qsB      = (float*)carve((size_t)N * 4);         // L2/L4
    int*   flags    = (int*)carve((size_t)256 * 4);
    short* wts      = (short*)carve((size_t)24576 * 2);
    unsigned* p_src = (unsigned*)carve((size_t)HIST_B * HWORDS * 4);   // 12.8 MB
    unsigned* p_dst = (unsigned*)carve((size_t)HIST_B * HWORDS * 4);   // 12.8 MB
    unsigned char* rank = (unsigned char*)carve((size_t)E);            // 0.8 MB
    (void)ws_size;

    short* w2h = wts;            short* w2l = w2h + 8704;
    short* w3h = w2l + 8704;     short* w3l = w3h + 2304;
    short* w4h = w3l + 2304;     short* w4l = w4h + 640;
    short* w5h = w4l + 640;      short* w5l = w5h + 640;   // end 24576

    const int chunk = (E + HIST_B - 1) / HIST_B;   // 3125
    const int gridG = (N + 63) / 64;               // 782

    // 1) packed front: gemm1 halves || hist || W2-5 split + flag zero
    packed0_kernel<<<G1BLKS + 2 * HIST_B + 49, THREADS, 0, stream>>>(
        x, W1, W2, W3, W4, W5, tqA, qsA, src, dst, p_src, p_dst, rank, flags,
        w2h, w2l, w3h, w3l, w4h, w4l, w5h, w5l, E, chunk, N);

    // 2) reduce + full scan (4-way chunk split + lookback)
    reduce_scan_kernel<<<RS_BLOCKS, THREADS, 0, stream>>>(
        p_src, p_dst, norm_src, norm_dst, qsA, row_ptr, flags, N);

    // 3) scatter -> col
    scatter_kernel<<<2 * HIST_B, THREADS, 0, stream>>>(src, dst, rank, row_ptr, p_dst, col, E, chunk);

    // 4-7) fused agg_l + gemm_{l+1}, ping-pong tq/qscale
    fused_agg_gemm_kernel<128, 64, true><<<gridG, THREADS, 0, stream>>>(
        tqA, qsA, row_ptr, col, norm_dst, b1, w2h, w2l, norm_src, tqB, qsB, N);
    fused_agg_gemm_kernel<64, 32, false><<<gridG, THREADS, 0, stream>>>(
        tqB, qsB, row_ptr, col, norm_dst, b2, w3h, w3l, norm_src, tqA, qsA, N);
    fused_agg_gemm_kernel<32, 16, false><<<gridG, THREADS, 0, stream>>>(
        tqA, qsA, row_ptr, col, norm_dst, b3, w4h, w4l, norm_src, tqB, qsB, N);
    fused_agg_gemm_kernel<16, 16, false><<<gridG, THREADS, 0, stream>>>(
        tqB, qsB, row_ptr, col, norm_dst, b4, w5h, w5l, norm_src, tqA, qsA, N);

    // 8) final aggregate -> d_out
    agg_q_kernel<16><<<(N + 127) / 128, THREADS, 0, stream>>>(
        tqA, qsA, row_ptr, col, norm_dst, b5, (float*)d_out, N);
}

// Round 12
// 269.822 us; speedup vs baseline: 1.0773x; 1.0773x over previous
//
#include <hip/hip_runtime.h>
#include <hip/hip_bf16.h>

// ---------------------------------------------------------------------------
// GCN: 5 layers of  h = relu( norm_dst * scatter_add( (h@W * norm_src)[src] ) + b )
// R12: selective fusion. R11's full fusion regressed: 68.6KB LDS on the big
// fused layer -> 2 blocks/CU -> 14.8% occupancy -> gather at 1.29 TB/s.
// Keep R10's separate agg1/gemm2 (occupancy-critical big gather), fuse only
// the small tail pairs where LDS stays <27KB: (agg2+gemm3), (agg3+gemm4),
// (agg4+gemm5). 9 launches.
// ---------------------------------------------------------------------------

#define THREADS 256
#define HIST_B 256          // edge chunks; hist uses 2*HIST_B blocks
#define HWORDS 12500        // u32 words, 4 nodes/word (8-bit counts), N=50000
#define RS_BLOCKS 196       // ceil(HWORDS/64)
#define G1BLKS 1564         // 2 * ceil(50000/64): gemm1 column-half blocks

typedef __attribute__((ext_vector_type(8))) short short8_t;
typedef __attribute__((ext_vector_type(4))) float float4_t;

__device__ __forceinline__ unsigned short f2bf_rne(float f) {
    unsigned u = __builtin_bit_cast(unsigned, f);
    unsigned r = u + 0x7fffu + ((u >> 16) & 1u);
    return (unsigned short)(r >> 16);
}
__device__ __forceinline__ float bf2f(unsigned short h) {
    return __builtin_bit_cast(float, ((unsigned)h) << 16);
}

// ---------------------------------------------------------------------------
// Split-bf16 MFMA quant epilogue (D: col=lane&15, row=quad*4+reg).
// ---------------------------------------------------------------------------
template<int NT, bool NORM>
__device__ __forceinline__ void quant_epilogue(float4_t* acc, const float* __restrict__ norm,
                                               short* __restrict__ outq, float* __restrict__ qscale,
                                               int M, int blk, int tid,
                                               int ostride, int ocol0, int qstride, int qoff) {
    const int w    = tid >> 6;
    const int lane = tid & 63;
    const int ln   = lane & 15;
    const int quad = lane >> 4;
    const int orow = blk * 64 + w * 16 + quad * 4;
#pragma unroll
    for (int i = 0; i < 4; ++i) {
        int r = orow + i;
        float m = 0.f;
#pragma unroll
        for (int nt = 0; nt < NT; ++nt) m = fmaxf(m, fabsf(acc[nt][i]));
#pragma unroll
        for (int off = 1; off < 16; off <<= 1) m = fmaxf(m, __shfl_xor(m, off));
        float s = 1.f;
        if (NORM) s = (r < M) ? norm[r] : 0.f;
        float rowmax = m * s;
        float inv = (rowmax > 0.f) ? (32767.f / rowmax) : 0.f;
        if (r < M) {
            if (ln == 0) qscale[r * qstride + qoff] = rowmax * (1.f / 32767.f);
#pragma unroll
            for (int nt = 0; nt < NT; ++nt)
                outq[(size_t)r * ostride + ocol0 + nt * 16 + ln] =
                    (short)(int)__builtin_rintf(acc[nt][i] * s * inv);
        }
    }
}

// MFMA core, A from global (row-major, width K). Layouts verified m89/m120.
template<int K, int NOUT, bool NORM>
__device__ __forceinline__ void gemm_core(const float* __restrict__ A,
                                          const short* lh, const short* ll,
                                          const float* __restrict__ norm,
                                          short* __restrict__ outq, float* __restrict__ qscale,
                                          int M, int blk, int tid,
                                          int ostride, int ocol0, int qstride, int qoff) {
    constexpr int Kp  = (K + 31) & ~31;
    constexpr int STR = Kp + 8;
    constexpr int NT  = NOUT / 16;
    const int w    = tid >> 6;
    const int lane = tid & 63;
    const int ln   = lane & 15;
    const int quad = lane >> 4;
    const int row  = blk * 64 + w * 16 + ln;
    const bool rv  = row < M;

    float4_t acc[NT];
#pragma unroll
    for (int i = 0; i < NT; ++i) acc[i] = (float4_t){0.f, 0.f, 0.f, 0.f};

#pragma unroll
    for (int kt = 0; kt < Kp / 32; ++kt) {
        const int k0 = kt * 32 + quad * 8;
        float a[8];
        if (rv && k0 < K) {
            float4 v0 = *(const float4*)&A[(size_t)row * K + k0];
            float4 v1 = *(const float4*)&A[(size_t)row * K + k0 + 4];
            a[0] = v0.x; a[1] = v0.y; a[2] = v0.z; a[3] = v0.w;
            a[4] = v1.x; a[5] = v1.y; a[6] = v1.z; a[7] = v1.w;
        } else {
#pragma unroll
            for (int j = 0; j < 8; ++j) a[j] = 0.f;
        }
        short8_t ahi, alo;
#pragma unroll
        for (int j = 0; j < 8; ++j) {
            unsigned short h = f2bf_rne(a[j]);
            ahi[j] = (short)h;
            alo[j] = (short)f2bf_rne(a[j] - bf2f(h));
        }
#pragma unroll
        for (int nt = 0; nt < NT; ++nt) {
            const int bidx = (nt * 16 + ln) * STR + kt * 32 + quad * 8;
            short8_t bh = *(const short8_t*)&lh[bidx];
            short8_t bl = *(const short8_t*)&ll[bidx];
            acc[nt] = __builtin_amdgcn_mfma_f32_16x16x32_bf16(ahi, bh, acc[nt], 0, 0, 0);
            acc[nt] = __builtin_amdgcn_mfma_f32_16x16x32_bf16(ahi, bl, acc[nt], 0, 0, 0);
            acc[nt] = __builtin_amdgcn_mfma_f32_16x16x32_bf16(alo, bh, acc[nt], 0, 0, 0);
        }
    }
    quant_epilogue<NT, NORM>(acc, norm, outq, qscale, M, blk, tid, ostride, ocol0, qstride, qoff);
}

// MFMA core, A from LDS (stride DINP floats, 64 local rows).
template<int K, int NOUT, int DINP>
__device__ __forceinline__ void gemm_core_lds(const float* As,
                                              const short* lh, const short* ll,
                                              const float* __restrict__ norm,
                                              short* __restrict__ outq, float* __restrict__ qscale,
                                              int M, int blk, int tid) {
    constexpr int Kp  = (K + 31) & ~31;
    constexpr int STR = Kp + 8;
    constexpr int NT  = NOUT / 16;
    const int w    = tid >> 6;
    const int lane = tid & 63;
    const int ln   = lane & 15;
    const int quad = lane >> 4;
    const int rloc = w * 16 + ln;
    const bool rv  = (blk * 64 + rloc) < M;

    float4_t acc[NT];
#pragma unroll
    for (int i = 0; i < NT; ++i) acc[i] = (float4_t){0.f, 0.f, 0.f, 0.f};

#pragma unroll
    for (int kt = 0; kt < Kp / 32; ++kt) {
        const int k0 = kt * 32 + quad * 8;
        float a[8];
        if (rv && k0 < K) {
            float4 v0 = *(const float4*)&As[rloc * DINP + k0];
            float4 v1 = *(const float4*)&As[rloc * DINP + k0 + 4];
            a[0] = v0.x; a[1] = v0.y; a[2] = v0.z; a[3] = v0.w;
            a[4] = v1.x; a[5] = v1.y; a[6] = v1.z; a[7] = v1.w;
        } else {
#pragma unroll
            for (int j = 0; j < 8; ++j) a[j] = 0.f;
        }
        short8_t ahi, alo;
#pragma unroll
        for (int j = 0; j < 8; ++j) {
            unsigned short h = f2bf_rne(a[j]);
            ahi[j] = (short)h;
            alo[j] = (short)f2bf_rne(a[j] - bf2f(h));
        }
#pragma unroll
        for (int nt = 0; nt < NT; ++nt) {
            const int bidx = (nt * 16 + ln) * STR + kt * 32 + quad * 8;
            short8_t bh = *(const short8_t*)&lh[bidx];
            short8_t bl = *(const short8_t*)&ll[bidx];
            acc[nt] = __builtin_amdgcn_mfma_f32_16x16x32_bf16(ahi, bh, acc[nt], 0, 0, 0);
            acc[nt] = __builtin_amdgcn_mfma_f32_16x16x32_bf16(ahi, bl, acc[nt], 0, 0, 0);
            acc[nt] = __builtin_amdgcn_mfma_f32_16x16x32_bf16(alo, bh, acc[nt], 0, 0, 0);
        }
    }
    quant_epilogue<NT, true>(acc, norm, outq, qscale, M, blk, tid, NOUT, 0, 1, 0);
}

// W pre-split element: W (KxNOUT fp32) -> W^T hi/lo bf16 [NOUT][STR shorts].
__device__ __forceinline__ void conv_one(const float* __restrict__ W, short* __restrict__ hi,
                                         short* __restrict__ lo, int K, int NOUT, int STR, int i) {
    int n = i / STR;
    int kk = i % STR;
    float v = (kk < K) ? W[(size_t)kk * NOUT + n] : 0.f;
    unsigned short h = f2bf_rne(v);
    hi[i] = (short)h;
    lo[i] = (short)f2bf_rne(v - bf2f(h));
}

// ---------------------------------------------------------------------------
// packed0: gemm1 column-halves (raw quant, per-half scales) || hist || W2-5
// split + flag zeroing. Static LDS 50,048 B -> 3 blocks/CU.
// ---------------------------------------------------------------------------
__global__ __launch_bounds__(THREADS)
void packed0_kernel(const float* __restrict__ x, const float* __restrict__ W1,
                    const float* __restrict__ W2, const float* __restrict__ W3,
                    const float* __restrict__ W4, const float* __restrict__ W5,
                    short* __restrict__ tq, float* __restrict__ qscale2,
                    const int* __restrict__ src, const int* __restrict__ dst,
                    unsigned* __restrict__ p_src, unsigned* __restrict__ p_dst,
                    unsigned char* __restrict__ rank, int* __restrict__ flags,
                    short* w2h, short* w2l, short* w3h, short* w3l,
                    short* w4h, short* w4l, short* w5h, short* w5l,
                    int E, int chunk, int N) {
    __shared__ __align__(16) char smem[50048];
    const int blk = blockIdx.x;
    const int t = threadIdx.x;

    if (blk < G1BLKS) {
        const int h  = blk & 1;
        const int gb = blk >> 1;
        short* lh = (short*)smem;           // 64*136 = 8704 shorts
        short* ll = (short*)smem + 8704;
        for (int j = t; j < 128 * 64; j += THREADS) {
            int kk = j >> 6, n = j & 63;
            float v = W1[kk * 128 + h * 64 + n];
            unsigned short hh = f2bf_rne(v);
            lh[n * 136 + kk] = (short)hh;
            ll[n * 136 + kk] = (short)f2bf_rne(v - bf2f(hh));
        }
        __syncthreads();
        gemm_core<128, 64, false>(x, lh, ll, nullptr, tq, qscale2, N, gb, t,
                                  128, h * 64, 2, h);
    } else if (blk < G1BLKS + 2 * HIST_B) {
        unsigned* bins = (unsigned*)smem;   // 50 KB
        const int hb = blk - G1BLKS;
        const bool is_dst = hb < HIST_B;
        const int b = is_dst ? hb : hb - HIST_B;
        const int e0 = b * chunk;
        int e1 = e0 + chunk; if (e1 > E) e1 = E;
        const int* __restrict__ idx = is_dst ? dst : src;
        unsigned* __restrict__ pout = is_dst ? p_dst : p_src;

        for (int w = t; w < HWORDS; w += THREADS) bins[w] = 0;
        __syncthreads();
        for (int e = e0 + t; e < e1; e += THREADS) {
            int d = idx[e];
            unsigned sh = (unsigned)(d & 3) * 8u;
            unsigned old = atomicAdd(&bins[d >> 2], 1u << sh);
            if (is_dst) rank[e] = (unsigned char)((old >> sh) & 0xffu);
        }
        __syncthreads();
        for (int w = t; w < HWORDS; w += THREADS)
            pout[(size_t)b * HWORDS + w] = bins[w];
    } else {
        int cb = blk - G1BLKS - 2 * HIST_B;     // 0..48
        if (cb == 48) {
            flags[t] = 0;
            return;
        }
        int i = cb * THREADS + t;
        if (i < 8704)                        conv_one(W2, w2h, w2l, 128, 64, 136, i);
        else if ((i -= 8704) < 2304)         conv_one(W3, w3h, w3l, 64, 32, 72, i);
        else if ((i -= 2304) < 640)          conv_one(W4, w4h, w4l, 32, 16, 40, i);
        else { i -= 640;                     conv_one(W5, w5h, w5l, 16, 16, 40, i); }
    }
}

// ---------------------------------------------------------------------------
// reduce_scan: 196 blocks, 64 words/block, 4 chunk-quarters/word; lookback.
// ---------------------------------------------------------------------------
__global__ __launch_bounds__(THREADS)
void reduce_scan_kernel(const unsigned* __restrict__ p_src, unsigned* __restrict__ p_dst,
                        float* __restrict__ norm_src, float* __restrict__ norm_dst,
                        float* __restrict__ qscale2, int* __restrict__ row_ptr,
                        int* __restrict__ flags, int N) {
    __shared__ unsigned qd[4][64];
    __shared__ unsigned qs[4][64];
    __shared__ int sscan[64];
    __shared__ int bexcl_sh;
    const int t  = threadIdx.x;
    const int b  = blockIdx.x;
    const int q  = t >> 6;
    const int wl = t & 63;
    const int w  = b * 64 + wl;
    const bool wv = (w < HWORDS);

    unsigned vals[64];
    unsigned dsum = 0, ssum = 0;
    if (wv) {
#pragma unroll
        for (int i = 0; i < 64; ++i) {
            int c = q * 64 + i;
            vals[i] = p_dst[(size_t)c * HWORDS + w];
            dsum += vals[i];
        }
#pragma unroll
        for (int i = 0; i < 64; ++i) {
            int c = q * 64 + i;
            ssum += p_src[(size_t)c * HWORDS + w];
        }
    }
    qd[q][wl] = dsum;
    qs[q][wl] = ssum;
    __syncthreads();

    unsigned off = 0, dfull = 0, sfull = 0;
#pragma unroll
    for (int qq = 0; qq < 4; ++qq) {
        unsigned v = qd[qq][wl];
        if (qq < q) off += v;
        dfull += v;
        sfull += qs[qq][wl];
    }

    if (wv) {
        unsigned run = off;
#pragma unroll
        for (int i = 0; i < 64; ++i) {
            int c = q * 64 + i;
            p_dst[(size_t)c * HWORDS + w] = run;
            run += vals[i];
        }
    }

    int d0 = 0, d1 = 0, d2 = 0, d3 = 0, wdeg = 0;
    if (q == 0) {
        d0 = (int)(dfull & 0xffu); d1 = (int)((dfull >> 8) & 0xffu);
        d2 = (int)((dfull >> 16) & 0xffu); d3 = (int)(dfull >> 24);
        wdeg = d0 + d1 + d2 + d3;
        if (wv) {
#pragma unroll
            for (int l = 0; l < 4; ++l) {
                int node = 4 * w + l;
                int dd = (l == 0) ? d0 : (l == 1) ? d1 : (l == 2) ? d2 : d3;
                int ds = (int)((sfull >> (8 * l)) & 0xffu);
                norm_dst[node] = rsqrtf((float)(dd < 1 ? 1 : dd));
                float ns = rsqrtf((float)(ds < 1 ? 1 : ds));
                norm_src[node] = ns;
                qscale2[2 * node]     *= ns;
                qscale2[2 * node + 1] *= ns;
            }
        }
        sscan[wl] = wv ? wdeg : 0;
    }
    __syncthreads();
    for (int o = 1; o < 64; o <<= 1) {
        int u = 0;
        if (t < 64 && t >= o) u = sscan[t - o];
        __syncthreads();
        if (t < 64) sscan[t] += u;
        __syncthreads();
    }
    const int btotal = sscan[63];

    if (t == 0) atomicExch(&flags[b], btotal + 1);
    if (t < 64) {
        int v = 0;
        for (int p = t; p < b; p += 64) {
            int f;
            do { f = atomicAdd(&flags[p], 0); } while (f == 0);
            v += f - 1;
        }
#pragma unroll
        for (int o = 1; o < 64; o <<= 1) v += __shfl_xor(v, o);
        if (t == 0) bexcl_sh = v;
    }
    __syncthreads();

    if (q == 0 && wv) {
        int pre = bexcl_sh + sscan[wl] - wdeg;
        int n0 = 4 * w;
        row_ptr[n0 + 0] = pre; pre += d0;
        row_ptr[n0 + 1] = pre; pre += d1;
        row_ptr[n0 + 2] = pre; pre += d2;
        row_ptr[n0 + 3] = pre;
    }
    if (b == RS_BLOCKS - 1 && t == 0) row_ptr[N] = bexcl_sh + btotal;
}

// ---------------------------------------------------------------------------
// scatter: 512 half-chunk blocks, precomputed rank bytes.
// ---------------------------------------------------------------------------
__global__ __launch_bounds__(THREADS)
void scatter_kernel(const int* __restrict__ src, const int* __restrict__ dst,
                    const unsigned char* __restrict__ rank,
                    const int* __restrict__ row_ptr, const unsigned* __restrict__ p_dst,
                    int* __restrict__ col, int E, int chunk) {
    const int bc = blockIdx.x >> 1;
    const int hch = (chunk + 1) >> 1;
    const int e0 = bc * chunk;
    int e1 = e0 + chunk; if (e1 > E) e1 = E;
    int s = e0 + (blockIdx.x & 1) * hch;
    int send = s + hch; if (send > e1) send = e1;
    for (int e = s + threadIdx.x; e < send; e += THREADS) {
        int d = dst[e];
        unsigned sh = (unsigned)(d & 3) * 8u;
        unsigned pre = (p_dst[(size_t)bc * HWORDS + (d >> 2)] >> sh) & 0xffu;
        col[row_ptr[d] + (int)pre + (int)rank[e]] = src[e];
    }
}

// ---------------------------------------------------------------------------
// Standalone GEMM (layer 2): stage pre-split W^T hi/lo, core with norm.
// ---------------------------------------------------------------------------
template<int K, int NOUT>
__global__ __launch_bounds__(THREADS)
void gemm_mfma_kernel(const float* __restrict__ A, const short* __restrict__ wt_hi,
                      const short* __restrict__ wt_lo, const float* __restrict__ norm,
                      short* __restrict__ outq, float* __restrict__ qscale, int M) {
    constexpr int Kp  = (K + 31) & ~31;
    constexpr int STR = Kp + 8;

    __shared__ short lh[NOUT * STR];
    __shared__ short ll[NOUT * STR];

    const int tid = threadIdx.x;
    {
        constexpr int CNT = NOUT * STR / 2;
        const int* gh = (const int*)wt_hi;
        const int* gl = (const int*)wt_lo;
        int* sh = (int*)lh;
        int* sl = (int*)ll;
        for (int i = tid; i < CNT; i += THREADS) { sh[i] = gh[i]; sl[i] = gl[i]; }
    }
    __syncthreads();
    gemm_core<K, NOUT, true>(A, lh, ll, norm, outq, qscale, M, blockIdx.x, tid,
                             NOUT, 0, 1, 0);
}

// ---------------------------------------------------------------------------
// Standalone int16 CSR aggregate (unroll-4). QS2: per-half scales (layer 1).
// FOUT=float out (hbuf or d_out).
// ---------------------------------------------------------------------------
template<int D, bool QS2>
__global__ __launch_bounds__(THREADS)
void agg_q_kernel(const short* __restrict__ tq, const float* __restrict__ qscale,
                  const int* __restrict__ row_ptr, const int* __restrict__ col,
                  const float* __restrict__ norm_dst, const float* __restrict__ bias,
                  float* __restrict__ out, int N) {
    constexpr int TPN = D / 8;
    constexpr int NPB = THREADS / TPN;
    const int tid  = threadIdx.x;
    const int ln   = tid % TPN;
    const int g    = tid / TPN;
    const int node = blockIdx.x * NPB + g;
    if (node >= N) return;

    const int half = QS2 ? (ln >> 3) : 0;
    const int beg = row_ptr[node];
    const int end = row_ptr[node + 1];

    float acc[8];
#pragma unroll
    for (int c = 0; c < 8; ++c) acc[c] = 0.f;

    auto scl = [&](int s) -> float {
        return QS2 ? qscale[2 * s + half] : qscale[s];
    };

    int j = beg;
    for (; j + 3 < end; j += 4) {
        int s0 = col[j], s1 = col[j + 1], s2 = col[j + 2], s3 = col[j + 3];
        short8_t v0 = *(const short8_t*)&tq[(size_t)s0 * D + ln * 8];
        short8_t v1 = *(const short8_t*)&tq[(size_t)s1 * D + ln * 8];
        short8_t v2 = *(const short8_t*)&tq[(size_t)s2 * D + ln * 8];
        short8_t v3 = *(const short8_t*)&tq[(size_t)s3 * D + ln * 8];
        float c0 = scl(s0), c1 = scl(s1), c2 = scl(s2), c3 = scl(s3);
#pragma unroll
        for (int c = 0; c < 8; ++c)
            acc[c] += (float)v0[c] * c0 + (float)v1[c] * c1
                    + (float)v2[c] * c2 + (float)v3[c] * c3;
    }
    for (; j < end; ++j) {
        int s0 = col[j];
        short8_t v0 = *(const short8_t*)&tq[(size_t)s0 * D + ln * 8];
        float c0 = scl(s0);
#pragma unroll
        for (int c = 0; c < 8; ++c) acc[c] += (float)v0[c] * c0;
    }

    float nd = norm_dst[node];
    float4 b0 = *(const float4*)&bias[ln * 8];
    float4 b1 = *(const float4*)&bias[ln * 8 + 4];
    float4 o0, o1;
    o0.x = fmaxf(acc[0] * nd + b0.x, 0.f);
    o0.y = fmaxf(acc[1] * nd + b0.y, 0.f);
    o0.z = fmaxf(acc[2] * nd + b0.z, 0.f);
    o0.w = fmaxf(acc[3] * nd + b0.w, 0.f);
    o1.x = fmaxf(acc[4] * nd + b1.x, 0.f);
    o1.y = fmaxf(acc[5] * nd + b1.y, 0.f);
    o1.z = fmaxf(acc[6] * nd + b1.z, 0.f);
    o1.w = fmaxf(acc[7] * nd + b1.w, 0.f);
    *(float4*)&out[(size_t)node * D + ln * 8] = o0;
    *(float4*)&out[(size_t)node * D + ln * 8 + 4] = o1;
}

// ---------------------------------------------------------------------------
// Fused agg_l + gemm_{l+1} for SMALL layers (LDS < 27KB): block aggregates
// its 64 nodes into LDS (stride DIN+4), relu+bias+norm_dst, then MFMA gemm.
// ---------------------------------------------------------------------------
template<int DIN, int NOUT>
__global__ __launch_bounds__(THREADS)
void fused_agg_gemm_kernel(const short* __restrict__ tq_in, const float* __restrict__ qs_in,
                           const int* __restrict__ row_ptr, const int* __restrict__ col,
                           const float* __restrict__ norm_dst, const float* __restrict__ bias,
                           const short* __restrict__ wt_hi, const short* __restrict__ wt_lo,
                           const float* __restrict__ norm_src,
                           short* __restrict__ tq_out, float* __restrict__ qs_out, int N) {
    constexpr int Kp   = (DIN + 31) & ~31;
    constexpr int STR  = Kp + 8;
    constexpr int DINP = DIN + 4;
    constexpr int TPN  = DIN / 8;

    __shared__ float As[64 * DINP];
    __shared__ short lh[NOUT * STR];
    __shared__ short ll[NOUT * STR];

    const int tid = threadIdx.x;
    {
        constexpr int CNT = NOUT * STR / 2;
        const int* gh = (const int*)wt_hi;
        const int* gl = (const int*)wt_lo;
        int* sh = (int*)lh;
        int* sl = (int*)ll;
        for (int i = tid; i < CNT; i += THREADS) { sh[i] = gh[i]; sl[i] = gl[i]; }
    }

    const int ln = tid % TPN;
    for (int n0 = tid / TPN; n0 < 64; n0 += THREADS / TPN) {
        const int node = blockIdx.x * 64 + n0;
        if (node < N) {
            const int beg = row_ptr[node];
            const int end = row_ptr[node + 1];
            float acc[8];
#pragma unroll
            for (int c = 0; c < 8; ++c) acc[c] = 0.f;
            int j = beg;
            for (; j + 3 < end; j += 4) {
                int s0 = col[j], s1 = col[j + 1], s2 = col[j + 2], s3 = col[j + 3];
                short8_t v0 = *(const short8_t*)&tq_in[(size_t)s0 * DIN + ln * 8];
                short8_t v1 = *(const short8_t*)&tq_in[(size_t)s1 * DIN + ln * 8];
                short8_t v2 = *(const short8_t*)&tq_in[(size_t)s2 * DIN + ln * 8];
                short8_t v3 = *(const short8_t*)&tq_in[(size_t)s3 * DIN + ln * 8];
                float c0 = qs_in[s0], c1 = qs_in[s1], c2 = qs_in[s2], c3 = qs_in[s3];
#pragma unroll
                for (int c = 0; c < 8; ++c)
                    acc[c] += (float)v0[c] * c0 + (float)v1[c] * c1
                            + (float)v2[c] * c2 + (float)v3[c] * c3;
            }
            for (; j < end; ++j) {
                int s0 = col[j];
                short8_t v0 = *(const short8_t*)&tq_in[(size_t)s0 * DIN + ln * 8];
                float c0 = qs_in[s0];
#pragma unroll
                for (int c = 0; c < 8; ++c) acc[c] += (float)v0[c] * c0;
            }
            float nd = norm_dst[node];
#pragma unroll
            for (int c = 0; c < 8; ++c)
                As[n0 * DINP + ln * 8 + c] = fmaxf(acc[c] * nd + bias[ln * 8 + c], 0.f);
        }
    }
    __syncthreads();

    gemm_core_lds<DIN, NOUT, DINP>(As, lh, ll, norm_src, tq_out, qs_out, N, blockIdx.x, tid);
}

extern "C" void kernel_launch(void* const* d_in, const int* in_sizes, int n_in,
                              void* d_out, int out_size, void* d_ws, size_t ws_size,
                              hipStream_t stream) {
    const float* x     = (const float*)d_in[0];
    const int*   edges = (const int*)d_in[1];
    const float* W1 = (const float*)d_in[2];  const float* b1 = (const float*)d_in[3];
    const float* W2 = (const float*)d_in[4];  const float* b2 = (const float*)d_in[5];
    const float* W3 = (const float*)d_in[6];  const float* b3 = (const float*)d_in[7];
    const float* W4 = (const float*)d_in[8];  const float* b4 = (const float*)d_in[9];
    const float* W5 = (const float*)d_in[10]; const float* b5 = (const float*)d_in[11];

    const int N = in_sizes[0] / 128;   // 50000
    const int E = in_sizes[1] / 2;     // 800000
    const int* src = edges;
    const int* dst = edges + E;

    // ---- carve workspace ----
    char* ws = (char*)d_ws;
    size_t off = 0;
    auto carve = [&](size_t bytes) -> void* {
        void* p = ws + off;
        off += (bytes + 255) & ~(size_t)255;
        return p;
    };
    short* tqA      = (short*)carve((size_t)N * 128 * 2);   // L1 out (128) / L2 out (64) / L4 out (16)
    short* tqB      = (short*)carve((size_t)N * 64 * 2);    // L3 out (32) / L5 out (16)
    float* hbuf     = (float*)carve((size_t)N * 128 * 4);   // agg1 output fp32
    float* norm_src = (float*)carve((size_t)N * 4);
    float* norm_dst = (float*)carve((size_t)N * 4);
    int*   row_ptr  = (int*)carve((size_t)(N + 1) * 4);
    int*   col      = (int*)carve((size_t)E * 4);
    float* qsA      = (float*)carve((size_t)2 * N * 4);     // L1 per-half; stride-1 reuse
    float* qsB      = (float*)carve((size_t)N * 4);
    int*   flags    = (int*)carve((size_t)256 * 4);
    short* wts      = (short*)carve((size_t)24576 * 2);
    unsigned* p_src = (unsigned*)carve((size_t)HIST_B * HWORDS * 4);   // 12.8 MB
    unsigned* p_dst = (unsigned*)carve((size_t)HIST_B * HWORDS * 4);   // 12.8 MB
    unsigned char* rank = (unsigned char*)carve((size_t)E);            // 0.8 MB
    (void)ws_size;

    short* w2h = wts;            short* w2l = w2h + 8704;
    short* w3h = w2l + 8704;     short* w3l = w3h + 2304;
    short* w4h = w3l + 2304;     short* w4l = w4h + 640;
    short* w5h = w4l + 640;      short* w5l = w5h + 640;   // end 24576

    const int chunk = (E + HIST_B - 1) / HIST_B;   // 3125
    const int gridG = (N + 63) / 64;               // 782

    // 1) packed front: gemm1 halves || hist || W2-5 split + flag zero
    packed0_kernel<<<G1BLKS + 2 * HIST_B + 49, THREADS, 0, stream>>>(
        x, W1, W2, W3, W4, W5, tqA, qsA, src, dst, p_src, p_dst, rank, flags,
        w2h, w2l, w3h, w3l, w4h, w4l, w5h, w5l, E, chunk, N);

    // 2) reduce + full scan (4-way chunk split + lookback)
    reduce_scan_kernel<<<RS_BLOCKS, THREADS, 0, stream>>>(
        p_src, p_dst, norm_src, norm_dst, qsA, row_ptr, flags, N);

    // 3) scatter -> col
    scatter_kernel<<<2 * HIST_B, THREADS, 0, stream>>>(src, dst, rank, row_ptr, p_dst, col, E, chunk);

    // 4) agg1 (standalone: occupancy-critical big gather)
    agg_q_kernel<128, true><<<(N + 15) / 16, THREADS, 0, stream>>>(
        tqA, qsA, row_ptr, col, norm_dst, b1, hbuf, N);

    // 5) gemm2 (standalone)
    gemm_mfma_kernel<128, 64><<<gridG, THREADS, 0, stream>>>(hbuf, w2h, w2l, norm_src, tqA, qsA, N);

    // 6-8) fused small layers: agg2+gemm3, agg3+gemm4, agg4+gemm5
    fused_agg_gemm_kernel<64, 32><<<gridG, THREADS, 0, stream>>>(
        tqA, qsA, row_ptr, col, norm_dst, b2, w3h, w3l, norm_src, tqB, qsB, N);
    fused_agg_gemm_kernel<32, 16><<<gridG, THREADS, 0, stream>>>(
        tqB, qsB, row_ptr, col, norm_dst, b3, w4h, w4l, norm_src, tqA, qsA, N);
    fused_agg_gemm_kernel<16, 16><<<gridG, THREADS, 0, stream>>>(
        tqA, qsA, row_ptr, col, norm_dst, b4, w5h, w5l, norm_src, tqB, qsB, N);

    // 9) final aggregate -> d_out
    agg_q_kernel<16, false><<<(N + 127) / 128, THREADS, 0, stream>>>(
        tqB, qsB, row_ptr, col, norm_dst, b5, (float*)d_out, N);
}

// Round 13
// 260.730 us; speedup vs baseline: 1.1148x; 1.0349x over previous
//
#include <hip/hip_runtime.h>
#include <hip/hip_bf16.h>

// ---------------------------------------------------------------------------
// GCN: 5 layers of  h = relu( norm_dst * scatter_add( (h@W * norm_src)[src] ) + b )
// R13: (a) agg1 edge-parallel x2 (32 lanes/node, shfl-combined) + int16
//     output w/ per-node scale (write 25.6->12.8MB); (b) gemm2 consumes int16
//     A directly (split-bf16 of int16 is exact; row scale folded into
//     epilogue; read 25.6->12.8MB); (c) HIST_B 256->128 (8-bit lanes safe:
//     per-chunk count <= degree <= ~45), halves hist partials to 12.8MB.
// ---------------------------------------------------------------------------

#define THREADS 256
#define HIST_B 128          // edge chunks; hist uses 2*HIST_B blocks
#define HWORDS 12500        // u32 words, 4 nodes/word (8-bit counts), N=50000
#define RS_BLOCKS 196       // ceil(HWORDS/64)
#define G1BLKS 1564         // 2 * ceil(50000/64): gemm1 column-half blocks
#define C4 (HIST_B / 4)     // chunks per quarter in reduce_scan (32)

typedef __attribute__((ext_vector_type(8))) short short8_t;
typedef __attribute__((ext_vector_type(4))) float float4_t;

__device__ __forceinline__ unsigned short f2bf_rne(float f) {
    unsigned u = __builtin_bit_cast(unsigned, f);
    unsigned r = u + 0x7fffu + ((u >> 16) & 1u);
    return (unsigned short)(r >> 16);
}
__device__ __forceinline__ float bf2f(unsigned short h) {
    return __builtin_bit_cast(float, ((unsigned)h) << 16);
}

// ---------------------------------------------------------------------------
// Split-bf16 MFMA quant epilogue (D: col=lane&15, row=quad*4+reg).
// ASCALE: extra per-row input scale (int16-A dequant) multiplied into s.
// ---------------------------------------------------------------------------
template<int NT, bool NORM, bool ASCALE>
__device__ __forceinline__ void quant_epilogue(float4_t* acc, const float* __restrict__ norm,
                                               const float* __restrict__ ascale,
                                               short* __restrict__ outq, float* __restrict__ qscale,
                                               int M, int blk, int tid,
                                               int ostride, int ocol0, int qstride, int qoff) {
    const int w    = tid >> 6;
    const int lane = tid & 63;
    const int ln   = lane & 15;
    const int quad = lane >> 4;
    const int orow = blk * 64 + w * 16 + quad * 4;
#pragma unroll
    for (int i = 0; i < 4; ++i) {
        int r = orow + i;
        float m = 0.f;
#pragma unroll
        for (int nt = 0; nt < NT; ++nt) m = fmaxf(m, fabsf(acc[nt][i]));
#pragma unroll
        for (int off = 1; off < 16; off <<= 1) m = fmaxf(m, __shfl_xor(m, off));
        float s = 1.f;
        if (NORM) s = (r < M) ? norm[r] : 0.f;
        if (ASCALE && r < M) s *= ascale[r];
        float rowmax = m * s;
        float inv = (rowmax > 0.f) ? (32767.f / rowmax) : 0.f;
        if (r < M) {
            if (ln == 0) qscale[r * qstride + qoff] = rowmax * (1.f / 32767.f);
#pragma unroll
            for (int nt = 0; nt < NT; ++nt)
                outq[(size_t)r * ostride + ocol0 + nt * 16 + ln] =
                    (short)(int)__builtin_rintf(acc[nt][i] * s * inv);
        }
    }
}

// MFMA core, A fp32 from global (row-major, width K). Layouts verified m89/m120.
template<int K, int NOUT, bool NORM>
__device__ __forceinline__ void gemm_core(const float* __restrict__ A,
                                          const short* lh, const short* ll,
                                          const float* __restrict__ norm,
                                          short* __restrict__ outq, float* __restrict__ qscale,
                                          int M, int blk, int tid,
                                          int ostride, int ocol0, int qstride, int qoff) {
    constexpr int Kp  = (K + 31) & ~31;
    constexpr int STR = Kp + 8;
    constexpr int NT  = NOUT / 16;
    const int w    = tid >> 6;
    const int lane = tid & 63;
    const int ln   = lane & 15;
    const int quad = lane >> 4;
    const int row  = blk * 64 + w * 16 + ln;
    const bool rv  = row < M;

    float4_t acc[NT];
#pragma unroll
    for (int i = 0; i < NT; ++i) acc[i] = (float4_t){0.f, 0.f, 0.f, 0.f};

#pragma unroll
    for (int kt = 0; kt < Kp / 32; ++kt) {
        const int k0 = kt * 32 + quad * 8;
        float a[8];
        if (rv && k0 < K) {
            float4 v0 = *(const float4*)&A[(size_t)row * K + k0];
            float4 v1 = *(const float4*)&A[(size_t)row * K + k0 + 4];
            a[0] = v0.x; a[1] = v0.y; a[2] = v0.z; a[3] = v0.w;
            a[4] = v1.x; a[5] = v1.y; a[6] = v1.z; a[7] = v1.w;
        } else {
#pragma unroll
            for (int j = 0; j < 8; ++j) a[j] = 0.f;
        }
        short8_t ahi, alo;
#pragma unroll
        for (int j = 0; j < 8; ++j) {
            unsigned short h = f2bf_rne(a[j]);
            ahi[j] = (short)h;
            alo[j] = (short)f2bf_rne(a[j] - bf2f(h));
        }
#pragma unroll
        for (int nt = 0; nt < NT; ++nt) {
            const int bidx = (nt * 16 + ln) * STR + kt * 32 + quad * 8;
            short8_t bh = *(const short8_t*)&lh[bidx];
            short8_t bl = *(const short8_t*)&ll[bidx];
            acc[nt] = __builtin_amdgcn_mfma_f32_16x16x32_bf16(ahi, bh, acc[nt], 0, 0, 0);
            acc[nt] = __builtin_amdgcn_mfma_f32_16x16x32_bf16(ahi, bl, acc[nt], 0, 0, 0);
            acc[nt] = __builtin_amdgcn_mfma_f32_16x16x32_bf16(alo, bh, acc[nt], 0, 0, 0);
        }
    }
    quant_epilogue<NT, NORM, false>(acc, norm, nullptr, outq, qscale, M, blk, tid,
                                    ostride, ocol0, qstride, qoff);
}

// MFMA core, A int16 from global (row-major, width K) + per-row scale folded
// into epilogue. Split-bf16 of int16 is exact (remainder <= 64).
template<int K, int NOUT>
__device__ __forceinline__ void gemm_core_q(const short* __restrict__ Aq,
                                            const float* __restrict__ ascale,
                                            const short* lh, const short* ll,
                                            const float* __restrict__ norm,
                                            short* __restrict__ outq, float* __restrict__ qscale,
                                            int M, int blk, int tid) {
    constexpr int Kp  = (K + 31) & ~31;
    constexpr int STR = Kp + 8;
    constexpr int NT  = NOUT / 16;
    const int w    = tid >> 6;
    const int lane = tid & 63;
    const int ln   = lane & 15;
    const int quad = lane >> 4;
    const int row  = blk * 64 + w * 16 + ln;
    const bool rv  = row < M;

    float4_t acc[NT];
#pragma unroll
    for (int i = 0; i < NT; ++i) acc[i] = (float4_t){0.f, 0.f, 0.f, 0.f};

#pragma unroll
    for (int kt = 0; kt < Kp / 32; ++kt) {
        const int k0 = kt * 32 + quad * 8;
        short8_t qv = (short8_t)(short)0;
        if (rv && k0 < K) qv = *(const short8_t*)&Aq[(size_t)row * K + k0];
        short8_t ahi, alo;
#pragma unroll
        for (int j = 0; j < 8; ++j) {
            float a = (float)qv[j];
            unsigned short h = f2bf_rne(a);
            ahi[j] = (short)h;
            alo[j] = (short)f2bf_rne(a - bf2f(h));
        }
#pragma unroll
        for (int nt = 0; nt < NT; ++nt) {
            const int bidx = (nt * 16 + ln) * STR + kt * 32 + quad * 8;
            short8_t bh = *(const short8_t*)&lh[bidx];
            short8_t bl = *(const short8_t*)&ll[bidx];
            acc[nt] = __builtin_amdgcn_mfma_f32_16x16x32_bf16(ahi, bh, acc[nt], 0, 0, 0);
            acc[nt] = __builtin_amdgcn_mfma_f32_16x16x32_bf16(ahi, bl, acc[nt], 0, 0, 0);
            acc[nt] = __builtin_amdgcn_mfma_f32_16x16x32_bf16(alo, bh, acc[nt], 0, 0, 0);
        }
    }
    quant_epilogue<NT, true, true>(acc, norm, ascale, outq, qscale, M, blk, tid,
                                   NOUT, 0, 1, 0);
}

// MFMA core, A fp32 from LDS (stride DINP floats, 64 local rows).
template<int K, int NOUT, int DINP>
__device__ __forceinline__ void gemm_core_lds(const float* As,
                                              const short* lh, const short* ll,
                                              const float* __restrict__ norm,
                                              short* __restrict__ outq, float* __restrict__ qscale,
                                              int M, int blk, int tid) {
    constexpr int Kp  = (K + 31) & ~31;
    constexpr int STR = Kp + 8;
    constexpr int NT  = NOUT / 16;
    const int w    = tid >> 6;
    const int lane = tid & 63;
    const int ln   = lane & 15;
    const int quad = lane >> 4;
    const int rloc = w * 16 + ln;
    const bool rv  = (blk * 64 + rloc) < M;

    float4_t acc[NT];
#pragma unroll
    for (int i = 0; i < NT; ++i) acc[i] = (float4_t){0.f, 0.f, 0.f, 0.f};

#pragma unroll
    for (int kt = 0; kt < Kp / 32; ++kt) {
        const int k0 = kt * 32 + quad * 8;
        float a[8];
        if (rv && k0 < K) {
            float4 v0 = *(const float4*)&As[rloc * DINP + k0];
            float4 v1 = *(const float4*)&As[rloc * DINP + k0 + 4];
            a[0] = v0.x; a[1] = v0.y; a[2] = v0.z; a[3] = v0.w;
            a[4] = v1.x; a[5] = v1.y; a[6] = v1.z; a[7] = v1.w;
        } else {
#pragma unroll
            for (int j = 0; j < 8; ++j) a[j] = 0.f;
        }
        short8_t ahi, alo;
#pragma unroll
        for (int j = 0; j < 8; ++j) {
            unsigned short h = f2bf_rne(a[j]);
            ahi[j] = (short)h;
            alo[j] = (short)f2bf_rne(a[j] - bf2f(h));
        }
#pragma unroll
        for (int nt = 0; nt < NT; ++nt) {
            const int bidx = (nt * 16 + ln) * STR + kt * 32 + quad * 8;
            short8_t bh = *(const short8_t*)&lh[bidx];
            short8_t bl = *(const short8_t*)&ll[bidx];
            acc[nt] = __builtin_amdgcn_mfma_f32_16x16x32_bf16(ahi, bh, acc[nt], 0, 0, 0);
            acc[nt] = __builtin_amdgcn_mfma_f32_16x16x32_bf16(ahi, bl, acc[nt], 0, 0, 0);
            acc[nt] = __builtin_amdgcn_mfma_f32_16x16x32_bf16(alo, bh, acc[nt], 0, 0, 0);
        }
    }
    quant_epilogue<NT, true, false>(acc, norm, nullptr, outq, qscale, M, blk, tid,
                                    NOUT, 0, 1, 0);
}

// W pre-split element: W (KxNOUT fp32) -> W^T hi/lo bf16 [NOUT][STR shorts].
__device__ __forceinline__ void conv_one(const float* __restrict__ W, short* __restrict__ hi,
                                         short* __restrict__ lo, int K, int NOUT, int STR, int i) {
    int n = i / STR;
    int kk = i % STR;
    float v = (kk < K) ? W[(size_t)kk * NOUT + n] : 0.f;
    unsigned short h = f2bf_rne(v);
    hi[i] = (short)h;
    lo[i] = (short)f2bf_rne(v - bf2f(h));
}

// ---------------------------------------------------------------------------
// packed0: gemm1 column-halves (raw quant, per-half scales) || hist (2*128
// blocks, 6250-edge chunks) || W2-5 split + flag zeroing. LDS 50,048 B.
// ---------------------------------------------------------------------------
__global__ __launch_bounds__(THREADS)
void packed0_kernel(const float* __restrict__ x, const float* __restrict__ W1,
                    const float* __restrict__ W2, const float* __restrict__ W3,
                    const float* __restrict__ W4, const float* __restrict__ W5,
                    short* __restrict__ tq, float* __restrict__ qscale2,
                    const int* __restrict__ src, const int* __restrict__ dst,
                    unsigned* __restrict__ p_src, unsigned* __restrict__ p_dst,
                    unsigned char* __restrict__ rank, int* __restrict__ flags,
                    short* w2h, short* w2l, short* w3h, short* w3l,
                    short* w4h, short* w4l, short* w5h, short* w5l,
                    int E, int chunk, int N) {
    __shared__ __align__(16) char smem[50048];
    const int blk = blockIdx.x;
    const int t = threadIdx.x;

    if (blk < G1BLKS) {
        const int h  = blk & 1;
        const int gb = blk >> 1;
        short* lh = (short*)smem;           // 64*136 = 8704 shorts
        short* ll = (short*)smem + 8704;
        for (int j = t; j < 128 * 64; j += THREADS) {
            int kk = j >> 6, n = j & 63;
            float v = W1[kk * 128 + h * 64 + n];
            unsigned short hh = f2bf_rne(v);
            lh[n * 136 + kk] = (short)hh;
            ll[n * 136 + kk] = (short)f2bf_rne(v - bf2f(hh));
        }
        __syncthreads();
        gemm_core<128, 64, false>(x, lh, ll, nullptr, tq, qscale2, N, gb, t,
                                  128, h * 64, 2, h);
    } else if (blk < G1BLKS + 2 * HIST_B) {
        unsigned* bins = (unsigned*)smem;   // 50 KB
        const int hb = blk - G1BLKS;
        const bool is_dst = hb < HIST_B;
        const int b = is_dst ? hb : hb - HIST_B;
        const int e0 = b * chunk;
        int e1 = e0 + chunk; if (e1 > E) e1 = E;
        const int* __restrict__ idx = is_dst ? dst : src;
        unsigned* __restrict__ pout = is_dst ? p_dst : p_src;

        for (int w = t; w < HWORDS; w += THREADS) bins[w] = 0;
        __syncthreads();
        for (int e = e0 + t; e < e1; e += THREADS) {
            int d = idx[e];
            unsigned sh = (unsigned)(d & 3) * 8u;
            unsigned old = atomicAdd(&bins[d >> 2], 1u << sh);
            if (is_dst) rank[e] = (unsigned char)((old >> sh) & 0xffu);
        }
        __syncthreads();
        for (int w = t; w < HWORDS; w += THREADS)
            pout[(size_t)b * HWORDS + w] = bins[w];
    } else {
        int cb = blk - G1BLKS - 2 * HIST_B;     // 0..48
        if (cb == 48) {
            flags[t] = 0;
            return;
        }
        int i = cb * THREADS + t;
        if (i < 8704)                        conv_one(W2, w2h, w2l, 128, 64, 136, i);
        else if ((i -= 8704) < 2304)         conv_one(W3, w3h, w3l, 64, 32, 72, i);
        else if ((i -= 2304) < 640)          conv_one(W4, w4h, w4l, 32, 16, 40, i);
        else { i -= 640;                     conv_one(W5, w5h, w5l, 16, 16, 40, i); }
    }
}

// ---------------------------------------------------------------------------
// reduce_scan: 196 blocks, 64 words/block, 4 chunk-quarters (32 chunks each);
// decoupled lookback -> row_ptr; folds norm_src into L1 per-half scales.
// ---------------------------------------------------------------------------
__global__ __launch_bounds__(THREADS)
void reduce_scan_kernel(const unsigned* __restrict__ p_src, unsigned* __restrict__ p_dst,
                        float* __restrict__ norm_src, float* __restrict__ norm_dst,
                        float* __restrict__ qscale2, int* __restrict__ row_ptr,
                        int* __restrict__ flags, int N) {
    __shared__ unsigned qd[4][64];
    __shared__ unsigned qs[4][64];
    __shared__ int sscan[64];
    __shared__ int bexcl_sh;
    const int t  = threadIdx.x;
    const int b  = blockIdx.x;
    const int q  = t >> 6;
    const int wl = t & 63;
    const int w  = b * 64 + wl;
    const bool wv = (w < HWORDS);

    unsigned vals[C4];
    unsigned dsum = 0, ssum = 0;
    if (wv) {
#pragma unroll
        for (int i = 0; i < C4; ++i) {
            int c = q * C4 + i;
            vals[i] = p_dst[(size_t)c * HWORDS + w];
            dsum += vals[i];
        }
#pragma unroll
        for (int i = 0; i < C4; ++i) {
            int c = q * C4 + i;
            ssum += p_src[(size_t)c * HWORDS + w];
        }
    }
    qd[q][wl] = dsum;
    qs[q][wl] = ssum;
    __syncthreads();

    unsigned off = 0, dfull = 0, sfull = 0;
#pragma unroll
    for (int qq = 0; qq < 4; ++qq) {
        unsigned v = qd[qq][wl];
        if (qq < q) off += v;
        dfull += v;
        sfull += qs[qq][wl];
    }

    if (wv) {
        unsigned run = off;
#pragma unroll
        for (int i = 0; i < C4; ++i) {
            int c = q * C4 + i;
            p_dst[(size_t)c * HWORDS + w] = run;
            run += vals[i];
        }
    }

    int d0 = 0, d1 = 0, d2 = 0, d3 = 0, wdeg = 0;
    if (q == 0) {
        d0 = (int)(dfull & 0xffu); d1 = (int)((dfull >> 8) & 0xffu);
        d2 = (int)((dfull >> 16) & 0xffu); d3 = (int)(dfull >> 24);
        wdeg = d0 + d1 + d2 + d3;
        if (wv) {
#pragma unroll
            for (int l = 0; l < 4; ++l) {
                int node = 4 * w + l;
                int dd = (l == 0) ? d0 : (l == 1) ? d1 : (l == 2) ? d2 : d3;
                int ds = (int)((sfull >> (8 * l)) & 0xffu);
                norm_dst[node] = rsqrtf((float)(dd < 1 ? 1 : dd));
                float ns = rsqrtf((float)(ds < 1 ? 1 : ds));
                norm_src[node] = ns;
                qscale2[2 * node]     *= ns;
                qscale2[2 * node + 1] *= ns;
            }
        }
        sscan[wl] = wv ? wdeg : 0;
    }
    __syncthreads();
    for (int o = 1; o < 64; o <<= 1) {
        int u = 0;
        if (t < 64 && t >= o) u = sscan[t - o];
        __syncthreads();
        if (t < 64) sscan[t] += u;
        __syncthreads();
    }
    const int btotal = sscan[63];

    if (t == 0) atomicExch(&flags[b], btotal + 1);
    if (t < 64) {
        int v = 0;
        for (int p = t; p < b; p += 64) {
            int f;
            do { f = atomicAdd(&flags[p], 0); } while (f == 0);
            v += f - 1;
        }
#pragma unroll
        for (int o = 1; o < 64; o <<= 1) v += __shfl_xor(v, o);
        if (t == 0) bexcl_sh = v;
    }
    __syncthreads();

    if (q == 0 && wv) {
        int pre = bexcl_sh + sscan[wl] - wdeg;
        int n0 = 4 * w;
        row_ptr[n0 + 0] = pre; pre += d0;
        row_ptr[n0 + 1] = pre; pre += d1;
        row_ptr[n0 + 2] = pre; pre += d2;
        row_ptr[n0 + 3] = pre;
    }
    if (b == RS_BLOCKS - 1 && t == 0) row_ptr[N] = bexcl_sh + btotal;
}

// ---------------------------------------------------------------------------
// scatter: 512 quarter-chunk blocks, precomputed rank bytes.
// ---------------------------------------------------------------------------
__global__ __launch_bounds__(THREADS)
void scatter_kernel(const int* __restrict__ src, const int* __restrict__ dst,
                    const unsigned char* __restrict__ rank,
                    const int* __restrict__ row_ptr, const unsigned* __restrict__ p_dst,
                    int* __restrict__ col, int E, int chunk) {
    const int bc  = blockIdx.x >> 2;
    const int sub = blockIdx.x & 3;
    const int qch = (chunk + 3) >> 2;
    const int e0 = bc * chunk;
    int e1 = e0 + chunk; if (e1 > E) e1 = E;
    int s = e0 + sub * qch;
    int send = s + qch; if (send > e1) send = e1;
    for (int e = s + threadIdx.x; e < send; e += THREADS) {
        int d = dst[e];
        unsigned sh = (unsigned)(d & 3) * 8u;
        unsigned pre = (p_dst[(size_t)bc * HWORDS + (d >> 2)] >> sh) & 0xffu;
        col[row_ptr[d] + (int)pre + (int)rank[e]] = src[e];
    }
}

// ---------------------------------------------------------------------------
// agg1: int16 gather with QS2 input scales, edge-parallel x2 (32 lanes/node),
// int16 + per-node scale OUTPUT. 8 nodes/block.
// ---------------------------------------------------------------------------
__global__ __launch_bounds__(THREADS)
void agg1_q_kernel(const short* __restrict__ tq, const float* __restrict__ qscale2,
                   const int* __restrict__ row_ptr, const int* __restrict__ col,
                   const float* __restrict__ norm_dst, const float* __restrict__ bias,
                   short* __restrict__ outq, float* __restrict__ qs_out, int N) {
    const int tid  = threadIdx.x;
    const int ln   = tid & 15;          // col lane: cols [ln*8, ln*8+8)
    const int ep   = (tid >> 4) & 1;    // edge parity
    const int g    = tid >> 5;          // node within block (0..7)
    const int node = blockIdx.x * 8 + g;
    if (node >= N) return;

    const int half = ln >> 3;
    const int beg = row_ptr[node];
    const int end = row_ptr[node + 1];

    float acc[8];
#pragma unroll
    for (int c = 0; c < 8; ++c) acc[c] = 0.f;

    int j = beg + ep;
    for (; j + 2 < end; j += 4) {
        int s0 = col[j];
        int s1 = col[j + 2];
        short8_t v0 = *(const short8_t*)&tq[(size_t)s0 * 128 + ln * 8];
        short8_t v1 = *(const short8_t*)&tq[(size_t)s1 * 128 + ln * 8];
        float c0 = qscale2[2 * s0 + half];
        float c1 = qscale2[2 * s1 + half];
#pragma unroll
        for (int c = 0; c < 8; ++c)
            acc[c] += (float)v0[c] * c0 + (float)v1[c] * c1;
    }
    if (j < end) {
        int s0 = col[j];
        short8_t v0 = *(const short8_t*)&tq[(size_t)s0 * 128 + ln * 8];
        float c0 = qscale2[2 * s0 + half];
#pragma unroll
        for (int c = 0; c < 8; ++c) acc[c] += (float)v0[c] * c0;
    }

    // combine edge parities (lanes differ in bit 4)
#pragma unroll
    for (int c = 0; c < 8; ++c) acc[c] += __shfl_xor(acc[c], 16);

    float nd = norm_dst[node];
    float vals[8];
    float m = 0.f;
#pragma unroll
    for (int c = 0; c < 8; ++c) {
        vals[c] = fmaxf(acc[c] * nd + bias[ln * 8 + c], 0.f);
        m = fmaxf(m, vals[c]);
    }
#pragma unroll
    for (int off = 1; off < 16; off <<= 1) m = fmaxf(m, __shfl_xor(m, off));
    float inv = (m > 0.f) ? (32767.f / m) : 0.f;

    if (ep == 0) {
        short8_t q;
#pragma unroll
        for (int c = 0; c < 8; ++c) q[c] = (short)(int)__builtin_rintf(vals[c] * inv);
        *(short8_t*)&outq[(size_t)node * 128 + ln * 8] = q;
        if (ln == 0) qs_out[node] = m * (1.f / 32767.f);
    }
}

// ---------------------------------------------------------------------------
// gemm2: int16 A (exact split-bf16) + per-row scale folded into epilogue.
// ---------------------------------------------------------------------------
template<int K, int NOUT>
__global__ __launch_bounds__(THREADS)
void gemm_mfma_q_kernel(const short* __restrict__ Aq, const float* __restrict__ ascale,
                        const short* __restrict__ wt_hi, const short* __restrict__ wt_lo,
                        const float* __restrict__ norm,
                        short* __restrict__ outq, float* __restrict__ qscale, int M) {
    constexpr int Kp  = (K + 31) & ~31;
    constexpr int STR = Kp + 8;

    __shared__ short lh[NOUT * STR];
    __shared__ short ll[NOUT * STR];

    const int tid = threadIdx.x;
    {
        constexpr int CNT = NOUT * STR / 2;
        const int* gh = (const int*)wt_hi;
        const int* gl = (const int*)wt_lo;
        int* sh = (int*)lh;
        int* sl = (int*)ll;
        for (int i = tid; i < CNT; i += THREADS) { sh[i] = gh[i]; sl[i] = gl[i]; }
    }
    __syncthreads();
    gemm_core_q<K, NOUT>(Aq, ascale, lh, ll, norm, outq, qscale, M, blockIdx.x, tid);
}

// ---------------------------------------------------------------------------
// Standalone int16 CSR aggregate (unroll-4), fp32 out (final layer).
// ---------------------------------------------------------------------------
template<int D>
__global__ __launch_bounds__(THREADS)
void agg_q_kernel(const short* __restrict__ tq, const float* __restrict__ qscale,
                  const int* __restrict__ row_ptr, const int* __restrict__ col,
                  const float* __restrict__ norm_dst, const float* __restrict__ bias,
                  float* __restrict__ out, int N) {
    constexpr int TPN = D / 8;
    constexpr int NPB = THREADS / TPN;
    const int tid  = threadIdx.x;
    const int ln   = tid % TPN;
    const int g    = tid / TPN;
    const int node = blockIdx.x * NPB + g;
    if (node >= N) return;

    const int beg = row_ptr[node];
    const int end = row_ptr[node + 1];

    float acc[8];
#pragma unroll
    for (int c = 0; c < 8; ++c) acc[c] = 0.f;

    int j = beg;
    for (; j + 3 < end; j += 4) {
        int s0 = col[j], s1 = col[j + 1], s2 = col[j + 2], s3 = col[j + 3];
        short8_t v0 = *(const short8_t*)&tq[(size_t)s0 * D + ln * 8];
        short8_t v1 = *(const short8_t*)&tq[(size_t)s1 * D + ln * 8];
        short8_t v2 = *(const short8_t*)&tq[(size_t)s2 * D + ln * 8];
        short8_t v3 = *(const short8_t*)&tq[(size_t)s3 * D + ln * 8];
        float c0 = qscale[s0], c1 = qscale[s1], c2 = qscale[s2], c3 = qscale[s3];
#pragma unroll
        for (int c = 0; c < 8; ++c)
            acc[c] += (float)v0[c] * c0 + (float)v1[c] * c1
                    + (float)v2[c] * c2 + (float)v3[c] * c3;
    }
    for (; j < end; ++j) {
        int s0 = col[j];
        short8_t v0 = *(const short8_t*)&tq[(size_t)s0 * D + ln * 8];
        float c0 = qscale[s0];
#pragma unroll
        for (int c = 0; c < 8; ++c) acc[c] += (float)v0[c] * c0;
    }

    float nd = norm_dst[node];
    float4 b0 = *(const float4*)&bias[ln * 8];
    float4 b1 = *(const float4*)&bias[ln * 8 + 4];
    float4 o0, o1;
    o0.x = fmaxf(acc[0] * nd + b0.x, 0.f);
    o0.y = fmaxf(acc[1] * nd + b0.y, 0.f);
    o0.z = fmaxf(acc[2] * nd + b0.z, 0.f);
    o0.w = fmaxf(acc[3] * nd + b0.w, 0.f);
    o1.x = fmaxf(acc[4] * nd + b1.x, 0.f);
    o1.y = fmaxf(acc[5] * nd + b1.y, 0.f);
    o1.z = fmaxf(acc[6] * nd + b1.z, 0.f);
    o1.w = fmaxf(acc[7] * nd + b1.w, 0.f);
    *(float4*)&out[(size_t)node * D + ln * 8] = o0;
    *(float4*)&out[(size_t)node * D + ln * 8 + 4] = o1;
}

// ---------------------------------------------------------------------------
// Fused agg_l + gemm_{l+1} for SMALL layers (LDS < 27KB).
// ---------------------------------------------------------------------------
template<int DIN, int NOUT>
__global__ __launch_bounds__(THREADS)
void fused_agg_gemm_kernel(const short* __restrict__ tq_in, const float* __restrict__ qs_in,
                           const int* __restrict__ row_ptr, const int* __restrict__ col,
                           const float* __restrict__ norm_dst, const float* __restrict__ bias,
                           const short* __restrict__ wt_hi, const short* __restrict__ wt_lo,
                           const float* __restrict__ norm_src,
                           short* __restrict__ tq_out, float* __restrict__ qs_out, int N) {
    constexpr int Kp   = (DIN + 31) & ~31;
    constexpr int STR  = Kp + 8;
    constexpr int DINP = DIN + 4;
    constexpr int TPN  = DIN / 8;

    __shared__ float As[64 * DINP];
    __shared__ short lh[NOUT * STR];
    __shared__ short ll[NOUT * STR];

    const int tid = threadIdx.x;
    {
        constexpr int CNT = NOUT * STR / 2;
        const int* gh = (const int*)wt_hi;
        const int* gl = (const int*)wt_lo;
        int* sh = (int*)lh;
        int* sl = (int*)ll;
        for (int i = tid; i < CNT; i += THREADS) { sh[i] = gh[i]; sl[i] = gl[i]; }
    }

    const int ln = tid % TPN;
    for (int n0 = tid / TPN; n0 < 64; n0 += THREADS / TPN) {
        const int node = blockIdx.x * 64 + n0;
        if (node < N) {
            const int beg = row_ptr[node];
            const int end = row_ptr[node + 1];
            float acc[8];
#pragma unroll
            for (int c = 0; c < 8; ++c) acc[c] = 0.f;
            int j = beg;
            for (; j + 3 < end; j += 4) {
                int s0 = col[j], s1 = col[j + 1], s2 = col[j + 2], s3 = col[j + 3];
                short8_t v0 = *(const short8_t*)&tq_in[(size_t)s0 * DIN + ln * 8];
                short8_t v1 = *(const short8_t*)&tq_in[(size_t)s1 * DIN + ln * 8];
                short8_t v2 = *(const short8_t*)&tq_in[(size_t)s2 * DIN + ln * 8];
                short8_t v3 = *(const short8_t*)&tq_in[(size_t)s3 * DIN + ln * 8];
                float c0 = qs_in[s0], c1 = qs_in[s1], c2 = qs_in[s2], c3 = qs_in[s3];
#pragma unroll
                for (int c = 0; c < 8; ++c)
                    acc[c] += (float)v0[c] * c0 + (float)v1[c] * c1
                            + (float)v2[c] * c2 + (float)v3[c] * c3;
            }
            for (; j < end; ++j) {
                int s0 = col[j];
                short8_t v0 = *(const short8_t*)&tq_in[(size_t)s0 * DIN + ln * 8];
                float c0 = qs_in[s0];
#pragma unroll
                for (int c = 0; c < 8; ++c) acc[c] += (float)v0[c] * c0;
            }
            float nd = norm_dst[node];
#pragma unroll
            for (int c = 0; c < 8; ++c)
                As[n0 * DINP + ln * 8 + c] = fmaxf(acc[c] * nd + bias[ln * 8 + c], 0.f);
        }
    }
    __syncthreads();

    gemm_core_lds<DIN, NOUT, DINP>(As, lh, ll, norm_src, tq_out, qs_out, N, blockIdx.x, tid);
}

extern "C" void kernel_launch(void* const* d_in, const int* in_sizes, int n_in,
                              void* d_out, int out_size, void* d_ws, size_t ws_size,
                              hipStream_t stream) {
    const float* x     = (const float*)d_in[0];
    const int*   edges = (const int*)d_in[1];
    const float* W1 = (const float*)d_in[2];  const float* b1 = (const float*)d_in[3];
    const float* W2 = (const float*)d_in[4];  const float* b2 = (const float*)d_in[5];
    const float* W3 = (const float*)d_in[6];  const float* b3 = (const float*)d_in[7];
    const float* W4 = (const float*)d_in[8];  const float* b4 = (const float*)d_in[9];
    const float* W5 = (const float*)d_in[10]; const float* b5 = (const float*)d_in[11];

    const int N = in_sizes[0] / 128;   // 50000
    const int E = in_sizes[1] / 2;     // 800000
    const int* src = edges;
    const int* dst = edges + E;

    // ---- carve workspace ----
    char* ws = (char*)d_ws;
    size_t off = 0;
    auto carve = [&](size_t bytes) -> void* {
        void* p = ws + off;
        off += (bytes + 255) & ~(size_t)255;
        return p;
    };
    short* tqA      = (short*)carve((size_t)N * 128 * 2);   // L1 out (128) / L2 out (64) / L4 out (16)
    short* tqB      = (short*)carve((size_t)N * 64 * 2);    // L3 out (32) / L5 out (16)
    short* tqH      = (short*)carve((size_t)N * 128 * 2);   // agg1 out (int16, 128)
    float* norm_src = (float*)carve((size_t)N * 4);
    float* norm_dst = (float*)carve((size_t)N * 4);
    int*   row_ptr  = (int*)carve((size_t)(N + 1) * 4);
    int*   col      = (int*)carve((size_t)E * 4);
    float* qsA      = (float*)carve((size_t)2 * N * 4);     // L1 per-half; stride-1 reuse
    float* qsB      = (float*)carve((size_t)N * 4);
    float* qsH      = (float*)carve((size_t)N * 4);         // agg1 per-node scale
    int*   flags    = (int*)carve((size_t)256 * 4);
    short* wts      = (short*)carve((size_t)24576 * 2);
    unsigned* p_src = (unsigned*)carve((size_t)HIST_B * HWORDS * 4);   // 6.4 MB
    unsigned* p_dst = (unsigned*)carve((size_t)HIST_B * HWORDS * 4);   // 6.4 MB
    unsigned char* rank = (unsigned char*)carve((size_t)E);            // 0.8 MB
    (void)ws_size;

    short* w2h = wts;            short* w2l = w2h + 8704;
    short* w3h = w2l + 8704;     short* w3l = w3h + 2304;
    short* w4h = w3l + 2304;     short* w4l = w4h + 640;
    short* w5h = w4l + 640;      short* w5l = w5h + 640;   // end 24576

    const int chunk = (E + HIST_B - 1) / HIST_B;   // 6250
    const int gridG = (N + 63) / 64;               // 782

    // 1) packed front: gemm1 halves || hist || W2-5 split + flag zero
    packed0_kernel<<<G1BLKS + 2 * HIST_B + 49, THREADS, 0, stream>>>(
        x, W1, W2, W3, W4, W5, tqA, qsA, src, dst, p_src, p_dst, rank, flags,
        w2h, w2l, w3h, w3l, w4h, w4l, w5h, w5l, E, chunk, N);

    // 2) reduce + full scan (4-way chunk split + lookback)
    reduce_scan_kernel<<<RS_BLOCKS, THREADS, 0, stream>>>(
        p_src, p_dst, norm_src, norm_dst, qsA, row_ptr, flags, N);

    // 3) scatter -> col (512 quarter-chunk blocks)
    scatter_kernel<<<4 * HIST_B, THREADS, 0, stream>>>(src, dst, rank, row_ptr, p_dst, col, E, chunk);

    // 4) agg1: edge-parallel x2, int16+scale output
    agg1_q_kernel<<<(N + 7) / 8, THREADS, 0, stream>>>(
        tqA, qsA, row_ptr, col, norm_dst, b1, tqH, qsH, N);

    // 5) gemm2: int16 A, row scale folded
    gemm_mfma_q_kernel<128, 64><<<gridG, THREADS, 0, stream>>>(
        tqH, qsH, w2h, w2l, norm_src, tqA, qsA, N);

    // 6-8) fused small layers
    fused_agg_gemm_kernel<64, 32><<<gridG, THREADS, 0, stream>>>(
        tqA, qsA, row_ptr, col, norm_dst, b2, w3h, w3l, norm_src, tqB, qsB, N);
    fused_agg_gemm_kernel<32, 16><<<gridG, THREADS, 0, stream>>>(
        tqB, qsB, row_ptr, col, norm_dst, b3, w4h, w4l, norm_src, tqA, qsA, N);
    fused_agg_gemm_kernel<16, 16><<<gridG, THREADS, 0, stream>>>(
        tqA, qsA, row_ptr, col, norm_dst, b4, w5h, w5l, norm_src, tqB, qsB, N);

    // 9) final aggregate -> d_out
    agg_q_kernel<16><<<(N + 127) / 128, THREADS, 0, stream>>>(
        tqB, qsB, row_ptr, col, norm_dst, b5, (float*)d_out, N);
}

// Round 14
// 259.472 us; speedup vs baseline: 1.1202x; 1.0048x over previous
//
#include <hip/hip_runtime.h>
#include <hip/hip_bf16.h>

// ---------------------------------------------------------------------------
// GCN: 5 layers of  h = relu( norm_dst * scatter_add( (h@W * norm_src)[src] ) + b )
// R14: gemm1 both-halves-per-block. R13's half-split made each x row be read
// and split-bf16-converted twice. Now each block converts its 64 rows' A
// fragments once into registers (32 VGPRs), then runs W-half 0 and W-half 1
// sequentially through the same 34.8KB LDS tile. LDS 50KB (3 blocks/CU
// preserved), gemm1 grid 1564->782, x traffic + conversion VALU halved.
// ---------------------------------------------------------------------------

#define THREADS 256
#define HIST_B 128          // edge chunks; hist uses 2*HIST_B blocks
#define HWORDS 12500        // u32 words, 4 nodes/word (8-bit counts), N=50000
#define RS_BLOCKS 196       // ceil(HWORDS/64)
#define G1BLKS 782          // ceil(50000/64): gemm1 blocks (both halves each)
#define C4 (HIST_B / 4)     // chunks per quarter in reduce_scan (32)

typedef __attribute__((ext_vector_type(8))) short short8_t;
typedef __attribute__((ext_vector_type(4))) float float4_t;

__device__ __forceinline__ unsigned short f2bf_rne(float f) {
    unsigned u = __builtin_bit_cast(unsigned, f);
    unsigned r = u + 0x7fffu + ((u >> 16) & 1u);
    return (unsigned short)(r >> 16);
}
__device__ __forceinline__ float bf2f(unsigned short h) {
    return __builtin_bit_cast(float, ((unsigned)h) << 16);
}

// ---------------------------------------------------------------------------
// Split-bf16 MFMA quant epilogue (D: col=lane&15, row=quad*4+reg).
// ASCALE: extra per-row input scale (int16-A dequant) multiplied into s.
// ---------------------------------------------------------------------------
template<int NT, bool NORM, bool ASCALE>
__device__ __forceinline__ void quant_epilogue(float4_t* acc, const float* __restrict__ norm,
                                               const float* __restrict__ ascale,
                                               short* __restrict__ outq, float* __restrict__ qscale,
                                               int M, int blk, int tid,
                                               int ostride, int ocol0, int qstride, int qoff) {
    const int w    = tid >> 6;
    const int lane = tid & 63;
    const int ln   = lane & 15;
    const int quad = lane >> 4;
    const int orow = blk * 64 + w * 16 + quad * 4;
#pragma unroll
    for (int i = 0; i < 4; ++i) {
        int r = orow + i;
        float m = 0.f;
#pragma unroll
        for (int nt = 0; nt < NT; ++nt) m = fmaxf(m, fabsf(acc[nt][i]));
#pragma unroll
        for (int off = 1; off < 16; off <<= 1) m = fmaxf(m, __shfl_xor(m, off));
        float s = 1.f;
        if (NORM) s = (r < M) ? norm[r] : 0.f;
        if (ASCALE && r < M) s *= ascale[r];
        float rowmax = m * s;
        float inv = (rowmax > 0.f) ? (32767.f / rowmax) : 0.f;
        if (r < M) {
            if (ln == 0) qscale[r * qstride + qoff] = rowmax * (1.f / 32767.f);
#pragma unroll
            for (int nt = 0; nt < NT; ++nt)
                outq[(size_t)r * ostride + ocol0 + nt * 16 + ln] =
                    (short)(int)__builtin_rintf(acc[nt][i] * s * inv);
        }
    }
}

// MFMA core, A int16 from global (row-major, width K) + per-row scale folded
// into epilogue. Split-bf16 of int16 is exact (remainder <= 64).
template<int K, int NOUT>
__device__ __forceinline__ void gemm_core_q(const short* __restrict__ Aq,
                                            const float* __restrict__ ascale,
                                            const short* lh, const short* ll,
                                            const float* __restrict__ norm,
                                            short* __restrict__ outq, float* __restrict__ qscale,
                                            int M, int blk, int tid) {
    constexpr int Kp  = (K + 31) & ~31;
    constexpr int STR = Kp + 8;
    constexpr int NT  = NOUT / 16;
    const int w    = tid >> 6;
    const int lane = tid & 63;
    const int ln   = lane & 15;
    const int quad = lane >> 4;
    const int row  = blk * 64 + w * 16 + ln;
    const bool rv  = row < M;

    float4_t acc[NT];
#pragma unroll
    for (int i = 0; i < NT; ++i) acc[i] = (float4_t){0.f, 0.f, 0.f, 0.f};

#pragma unroll
    for (int kt = 0; kt < Kp / 32; ++kt) {
        const int k0 = kt * 32 + quad * 8;
        short8_t qv = (short8_t)(short)0;
        if (rv && k0 < K) qv = *(const short8_t*)&Aq[(size_t)row * K + k0];
        short8_t ahi, alo;
#pragma unroll
        for (int j = 0; j < 8; ++j) {
            float a = (float)qv[j];
            unsigned short h = f2bf_rne(a);
            ahi[j] = (short)h;
            alo[j] = (short)f2bf_rne(a - bf2f(h));
        }
#pragma unroll
        for (int nt = 0; nt < NT; ++nt) {
            const int bidx = (nt * 16 + ln) * STR + kt * 32 + quad * 8;
            short8_t bh = *(const short8_t*)&lh[bidx];
            short8_t bl = *(const short8_t*)&ll[bidx];
            acc[nt] = __builtin_amdgcn_mfma_f32_16x16x32_bf16(ahi, bh, acc[nt], 0, 0, 0);
            acc[nt] = __builtin_amdgcn_mfma_f32_16x16x32_bf16(ahi, bl, acc[nt], 0, 0, 0);
            acc[nt] = __builtin_amdgcn_mfma_f32_16x16x32_bf16(alo, bh, acc[nt], 0, 0, 0);
        }
    }
    quant_epilogue<NT, true, true>(acc, norm, ascale, outq, qscale, M, blk, tid,
                                   NOUT, 0, 1, 0);
}

// MFMA core, A fp32 from LDS (stride DINP floats, 64 local rows).
template<int K, int NOUT, int DINP>
__device__ __forceinline__ void gemm_core_lds(const float* As,
                                              const short* lh, const short* ll,
                                              const float* __restrict__ norm,
                                              short* __restrict__ outq, float* __restrict__ qscale,
                                              int M, int blk, int tid) {
    constexpr int Kp  = (K + 31) & ~31;
    constexpr int STR = Kp + 8;
    constexpr int NT  = NOUT / 16;
    const int w    = tid >> 6;
    const int lane = tid & 63;
    const int ln   = lane & 15;
    const int quad = lane >> 4;
    const int rloc = w * 16 + ln;
    const bool rv  = (blk * 64 + rloc) < M;

    float4_t acc[NT];
#pragma unroll
    for (int i = 0; i < NT; ++i) acc[i] = (float4_t){0.f, 0.f, 0.f, 0.f};

#pragma unroll
    for (int kt = 0; kt < Kp / 32; ++kt) {
        const int k0 = kt * 32 + quad * 8;
        float a[8];
        if (rv && k0 < K) {
            float4 v0 = *(const float4*)&As[rloc * DINP + k0];
            float4 v1 = *(const float4*)&As[rloc * DINP + k0 + 4];
            a[0] = v0.x; a[1] = v0.y; a[2] = v0.z; a[3] = v0.w;
            a[4] = v1.x; a[5] = v1.y; a[6] = v1.z; a[7] = v1.w;
        } else {
#pragma unroll
            for (int j = 0; j < 8; ++j) a[j] = 0.f;
        }
        short8_t ahi, alo;
#pragma unroll
        for (int j = 0; j < 8; ++j) {
            unsigned short h = f2bf_rne(a[j]);
            ahi[j] = (short)h;
            alo[j] = (short)f2bf_rne(a[j] - bf2f(h));
        }
#pragma unroll
        for (int nt = 0; nt < NT; ++nt) {
            const int bidx = (nt * 16 + ln) * STR + kt * 32 + quad * 8;
            short8_t bh = *(const short8_t*)&lh[bidx];
            short8_t bl = *(const short8_t*)&ll[bidx];
            acc[nt] = __builtin_amdgcn_mfma_f32_16x16x32_bf16(ahi, bh, acc[nt], 0, 0, 0);
            acc[nt] = __builtin_amdgcn_mfma_f32_16x16x32_bf16(ahi, bl, acc[nt], 0, 0, 0);
            acc[nt] = __builtin_amdgcn_mfma_f32_16x16x32_bf16(alo, bh, acc[nt], 0, 0, 0);
        }
    }
    quant_epilogue<NT, true, false>(acc, norm, nullptr, outq, qscale, M, blk, tid,
                                    NOUT, 0, 1, 0);
}

// W pre-split element: W (KxNOUT fp32) -> W^T hi/lo bf16 [NOUT][STR shorts].
__device__ __forceinline__ void conv_one(const float* __restrict__ W, short* __restrict__ hi,
                                         short* __restrict__ lo, int K, int NOUT, int STR, int i) {
    int n = i / STR;
    int kk = i % STR;
    float v = (kk < K) ? W[(size_t)kk * NOUT + n] : 0.f;
    unsigned short h = f2bf_rne(v);
    hi[i] = (short)h;
    lo[i] = (short)f2bf_rne(v - bf2f(h));
}

// ---------------------------------------------------------------------------
// packed0: gemm1 (both W1 halves per block: A converted ONCE to registers,
// W halves staged sequentially through one 34.8KB LDS tile) || hist || W2-5
// split + flag zeroing. Static LDS 50,048 B -> 3 blocks/CU.
// ---------------------------------------------------------------------------
__global__ __launch_bounds__(THREADS)
void packed0_kernel(const float* __restrict__ x, const float* __restrict__ W1,
                    const float* __restrict__ W2, const float* __restrict__ W3,
                    const float* __restrict__ W4, const float* __restrict__ W5,
                    short* __restrict__ tq, float* __restrict__ qscale2,
                    const int* __restrict__ src, const int* __restrict__ dst,
                    unsigned* __restrict__ p_src, unsigned* __restrict__ p_dst,
                    unsigned char* __restrict__ rank, int* __restrict__ flags,
                    short* w2h, short* w2l, short* w3h, short* w3l,
                    short* w4h, short* w4l, short* w5h, short* w5l,
                    int E, int chunk, int N) {
    __shared__ __align__(16) char smem[50048];
    const int blk = blockIdx.x;
    const int t = threadIdx.x;

    if (blk < G1BLKS) {
        // ---- gemm1: convert A fragments once, run both W1 column-halves ----
        short* lh = (short*)smem;           // 64*136 = 8704 shorts
        short* ll = (short*)smem + 8704;

        const int lane = t & 63;
        const int ln   = lane & 15;
        const int quad = lane >> 4;
        const int row  = blk * 64 + (t >> 6) * 16 + ln;
        const bool rv  = row < N;

        short8_t ahi[4], alo[4];
#pragma unroll
        for (int kt = 0; kt < 4; ++kt) {
            const int k0 = kt * 32 + quad * 8;
            float a[8];
            if (rv) {
                float4 v0 = *(const float4*)&x[(size_t)row * 128 + k0];
                float4 v1 = *(const float4*)&x[(size_t)row * 128 + k0 + 4];
                a[0] = v0.x; a[1] = v0.y; a[2] = v0.z; a[3] = v0.w;
                a[4] = v1.x; a[5] = v1.y; a[6] = v1.z; a[7] = v1.w;
            } else {
#pragma unroll
                for (int j = 0; j < 8; ++j) a[j] = 0.f;
            }
#pragma unroll
            for (int j = 0; j < 8; ++j) {
                unsigned short h = f2bf_rne(a[j]);
                ahi[kt][j] = (short)h;
                alo[kt][j] = (short)f2bf_rne(a[j] - bf2f(h));
            }
        }

        for (int h = 0; h < 2; ++h) {
            // stage W1 half h (cols [h*64, h*64+64))
            for (int j = t; j < 128 * 64; j += THREADS) {
                int kk = j >> 6, n = j & 63;
                float v = W1[kk * 128 + h * 64 + n];
                unsigned short hh = f2bf_rne(v);
                lh[n * 136 + kk] = (short)hh;
                ll[n * 136 + kk] = (short)f2bf_rne(v - bf2f(hh));
            }
            __syncthreads();

            float4_t acc[4];
#pragma unroll
            for (int i = 0; i < 4; ++i) acc[i] = (float4_t){0.f, 0.f, 0.f, 0.f};
#pragma unroll
            for (int kt = 0; kt < 4; ++kt) {
#pragma unroll
                for (int nt = 0; nt < 4; ++nt) {
                    const int bidx = (nt * 16 + ln) * 136 + kt * 32 + quad * 8;
                    short8_t bh = *(const short8_t*)&lh[bidx];
                    short8_t bl = *(const short8_t*)&ll[bidx];
                    acc[nt] = __builtin_amdgcn_mfma_f32_16x16x32_bf16(ahi[kt], bh, acc[nt], 0, 0, 0);
                    acc[nt] = __builtin_amdgcn_mfma_f32_16x16x32_bf16(ahi[kt], bl, acc[nt], 0, 0, 0);
                    acc[nt] = __builtin_amdgcn_mfma_f32_16x16x32_bf16(alo[kt], bh, acc[nt], 0, 0, 0);
                }
            }
            quant_epilogue<4, false, false>(acc, nullptr, nullptr, tq, qscale2, N, blk, t,
                                            128, h * 64, 2, h);
            if (h == 0) __syncthreads();   // LDS reuse barrier before half 1 staging
        }
    } else if (blk < G1BLKS + 2 * HIST_B) {
        unsigned* bins = (unsigned*)smem;   // 50 KB
        const int hb = blk - G1BLKS;
        const bool is_dst = hb < HIST_B;
        const int b = is_dst ? hb : hb - HIST_B;
        const int e0 = b * chunk;
        int e1 = e0 + chunk; if (e1 > E) e1 = E;
        const int* __restrict__ idx = is_dst ? dst : src;
        unsigned* __restrict__ pout = is_dst ? p_dst : p_src;

        for (int w = t; w < HWORDS; w += THREADS) bins[w] = 0;
        __syncthreads();
        for (int e = e0 + t; e < e1; e += THREADS) {
            int d = idx[e];
            unsigned sh = (unsigned)(d & 3) * 8u;
            unsigned old = atomicAdd(&bins[d >> 2], 1u << sh);
            if (is_dst) rank[e] = (unsigned char)((old >> sh) & 0xffu);
        }
        __syncthreads();
        for (int w = t; w < HWORDS; w += THREADS)
            pout[(size_t)b * HWORDS + w] = bins[w];
    } else {
        int cb = blk - G1BLKS - 2 * HIST_B;     // 0..48
        if (cb == 48) {
            flags[t] = 0;
            return;
        }
        int i = cb * THREADS + t;
        if (i < 8704)                        conv_one(W2, w2h, w2l, 128, 64, 136, i);
        else if ((i -= 8704) < 2304)         conv_one(W3, w3h, w3l, 64, 32, 72, i);
        else if ((i -= 2304) < 640)          conv_one(W4, w4h, w4l, 32, 16, 40, i);
        else { i -= 640;                     conv_one(W5, w5h, w5l, 16, 16, 40, i); }
    }
}

// ---------------------------------------------------------------------------
// reduce_scan: 196 blocks, 64 words/block, 4 chunk-quarters (32 chunks each);
// decoupled lookback -> row_ptr; folds norm_src into L1 per-half scales.
// ---------------------------------------------------------------------------
__global__ __launch_bounds__(THREADS)
void reduce_scan_kernel(const unsigned* __restrict__ p_src, unsigned* __restrict__ p_dst,
                        float* __restrict__ norm_src, float* __restrict__ norm_dst,
                        float* __restrict__ qscale2, int* __restrict__ row_ptr,
                        int* __restrict__ flags, int N) {
    __shared__ unsigned qd[4][64];
    __shared__ unsigned qs[4][64];
    __shared__ int sscan[64];
    __shared__ int bexcl_sh;
    const int t  = threadIdx.x;
    const int b  = blockIdx.x;
    const int q  = t >> 6;
    const int wl = t & 63;
    const int w  = b * 64 + wl;
    const bool wv = (w < HWORDS);

    unsigned vals[C4];
    unsigned dsum = 0, ssum = 0;
    if (wv) {
#pragma unroll
        for (int i = 0; i < C4; ++i) {
            int c = q * C4 + i;
            vals[i] = p_dst[(size_t)c * HWORDS + w];
            dsum += vals[i];
        }
#pragma unroll
        for (int i = 0; i < C4; ++i) {
            int c = q * C4 + i;
            ssum += p_src[(size_t)c * HWORDS + w];
        }
    }
    qd[q][wl] = dsum;
    qs[q][wl] = ssum;
    __syncthreads();

    unsigned off = 0, dfull = 0, sfull = 0;
#pragma unroll
    for (int qq = 0; qq < 4; ++qq) {
        unsigned v = qd[qq][wl];
        if (qq < q) off += v;
        dfull += v;
        sfull += qs[qq][wl];
    }

    if (wv) {
        unsigned run = off;
#pragma unroll
        for (int i = 0; i < C4; ++i) {
            int c = q * C4 + i;
            p_dst[(size_t)c * HWORDS + w] = run;
            run += vals[i];
        }
    }

    int d0 = 0, d1 = 0, d2 = 0, d3 = 0, wdeg = 0;
    if (q == 0) {
        d0 = (int)(dfull & 0xffu); d1 = (int)((dfull >> 8) & 0xffu);
        d2 = (int)((dfull >> 16) & 0xffu); d3 = (int)(dfull >> 24);
        wdeg = d0 + d1 + d2 + d3;
        if (wv) {
#pragma unroll
            for (int l = 0; l < 4; ++l) {
                int node = 4 * w + l;
                int dd = (l == 0) ? d0 : (l == 1) ? d1 : (l == 2) ? d2 : d3;
                int ds = (int)((sfull >> (8 * l)) & 0xffu);
                norm_dst[node] = rsqrtf((float)(dd < 1 ? 1 : dd));
                float ns = rsqrtf((float)(ds < 1 ? 1 : ds));
                norm_src[node] = ns;
                qscale2[2 * node]     *= ns;
                qscale2[2 * node + 1] *= ns;
            }
        }
        sscan[wl] = wv ? wdeg : 0;
    }
    __syncthreads();
    for (int o = 1; o < 64; o <<= 1) {
        int u = 0;
        if (t < 64 && t >= o) u = sscan[t - o];
        __syncthreads();
        if (t < 64) sscan[t] += u;
        __syncthreads();
    }
    const int btotal = sscan[63];

    if (t == 0) atomicExch(&flags[b], btotal + 1);
    if (t < 64) {
        int v = 0;
        for (int p = t; p < b; p += 64) {
            int f;
            do { f = atomicAdd(&flags[p], 0); } while (f == 0);
            v += f - 1;
        }
#pragma unroll
        for (int o = 1; o < 64; o <<= 1) v += __shfl_xor(v, o);
        if (t == 0) bexcl_sh = v;
    }
    __syncthreads();

    if (q == 0 && wv) {
        int pre = bexcl_sh + sscan[wl] - wdeg;
        int n0 = 4 * w;
        row_ptr[n0 + 0] = pre; pre += d0;
        row_ptr[n0 + 1] = pre; pre += d1;
        row_ptr[n0 + 2] = pre; pre += d2;
        row_ptr[n0 + 3] = pre;
    }
    if (b == RS_BLOCKS - 1 && t == 0) row_ptr[N] = bexcl_sh + btotal;
}

// ---------------------------------------------------------------------------
// scatter: 512 quarter-chunk blocks, precomputed rank bytes.
// ---------------------------------------------------------------------------
__global__ __launch_bounds__(THREADS)
void scatter_kernel(const int* __restrict__ src, const int* __restrict__ dst,
                    const unsigned char* __restrict__ rank,
                    const int* __restrict__ row_ptr, const unsigned* __restrict__ p_dst,
                    int* __restrict__ col, int E, int chunk) {
    const int bc  = blockIdx.x >> 2;
    const int sub = blockIdx.x & 3;
    const int qch = (chunk + 3) >> 2;
    const int e0 = bc * chunk;
    int e1 = e0 + chunk; if (e1 > E) e1 = E;
    int s = e0 + sub * qch;
    int send = s + qch; if (send > e1) send = e1;
    for (int e = s + threadIdx.x; e < send; e += THREADS) {
        int d = dst[e];
        unsigned sh = (unsigned)(d & 3) * 8u;
        unsigned pre = (p_dst[(size_t)bc * HWORDS + (d >> 2)] >> sh) & 0xffu;
        col[row_ptr[d] + (int)pre + (int)rank[e]] = src[e];
    }
}

// ---------------------------------------------------------------------------
// agg1: int16 gather with QS2 input scales, edge-parallel x2 (32 lanes/node),
// int16 + per-node scale OUTPUT. 8 nodes/block.
// ---------------------------------------------------------------------------
__global__ __launch_bounds__(THREADS)
void agg1_q_kernel(const short* __restrict__ tq, const float* __restrict__ qscale2,
                   const int* __restrict__ row_ptr, const int* __restrict__ col,
                   const float* __restrict__ norm_dst, const float* __restrict__ bias,
                   short* __restrict__ outq, float* __restrict__ qs_out, int N) {
    const int tid  = threadIdx.x;
    const int ln   = tid & 15;          // col lane: cols [ln*8, ln*8+8)
    const int ep   = (tid >> 4) & 1;    // edge parity
    const int g    = tid >> 5;          // node within block (0..7)
    const int node = blockIdx.x * 8 + g;
    if (node >= N) return;

    const int half = ln >> 3;
    const int beg = row_ptr[node];
    const int end = row_ptr[node + 1];

    float acc[8];
#pragma unroll
    for (int c = 0; c < 8; ++c) acc[c] = 0.f;

    int j = beg + ep;
    for (; j + 2 < end; j += 4) {
        int s0 = col[j];
        int s1 = col[j + 2];
        short8_t v0 = *(const short8_t*)&tq[(size_t)s0 * 128 + ln * 8];
        short8_t v1 = *(const short8_t*)&tq[(size_t)s1 * 128 + ln * 8];
        float c0 = qscale2[2 * s0 + half];
        float c1 = qscale2[2 * s1 + half];
#pragma unroll
        for (int c = 0; c < 8; ++c)
            acc[c] += (float)v0[c] * c0 + (float)v1[c] * c1;
    }
    if (j < end) {
        int s0 = col[j];
        short8_t v0 = *(const short8_t*)&tq[(size_t)s0 * 128 + ln * 8];
        float c0 = qscale2[2 * s0 + half];
#pragma unroll
        for (int c = 0; c < 8; ++c) acc[c] += (float)v0[c] * c0;
    }

    // combine edge parities (lanes differ in bit 4)
#pragma unroll
    for (int c = 0; c < 8; ++c) acc[c] += __shfl_xor(acc[c], 16);

    float nd = norm_dst[node];
    float vals[8];
    float m = 0.f;
#pragma unroll
    for (int c = 0; c < 8; ++c) {
        vals[c] = fmaxf(acc[c] * nd + bias[ln * 8 + c], 0.f);
        m = fmaxf(m, vals[c]);
    }
#pragma unroll
    for (int off = 1; off < 16; off <<= 1) m = fmaxf(m, __shfl_xor(m, off));
    float inv = (m > 0.f) ? (32767.f / m) : 0.f;

    if (ep == 0) {
        short8_t q;
#pragma unroll
        for (int c = 0; c < 8; ++c) q[c] = (short)(int)__builtin_rintf(vals[c] * inv);
        *(short8_t*)&outq[(size_t)node * 128 + ln * 8] = q;
        if (ln == 0) qs_out[node] = m * (1.f / 32767.f);
    }
}

// ---------------------------------------------------------------------------
// gemm2: int16 A (exact split-bf16) + per-row scale folded into epilogue.
// ---------------------------------------------------------------------------
template<int K, int NOUT>
__global__ __launch_bounds__(THREADS)
void gemm_mfma_q_kernel(const short* __restrict__ Aq, const float* __restrict__ ascale,
                        const short* __restrict__ wt_hi, const short* __restrict__ wt_lo,
                        const float* __restrict__ norm,
                        short* __restrict__ outq, float* __restrict__ qscale, int M) {
    constexpr int Kp  = (K + 31) & ~31;
    constexpr int STR = Kp + 8;

    __shared__ short lh[NOUT * STR];
    __shared__ short ll[NOUT * STR];

    const int tid = threadIdx.x;
    {
        constexpr int CNT = NOUT * STR / 2;
        const int* gh = (const int*)wt_hi;
        const int* gl = (const int*)wt_lo;
        int* sh = (int*)lh;
        int* sl = (int*)ll;
        for (int i = tid; i < CNT; i += THREADS) { sh[i] = gh[i]; sl[i] = gl[i]; }
    }
    __syncthreads();
    gemm_core_q<K, NOUT>(Aq, ascale, lh, ll, norm, outq, qscale, M, blockIdx.x, tid);
}

// ---------------------------------------------------------------------------
// Standalone int16 CSR aggregate (unroll-4), fp32 out (final layer).
// ---------------------------------------------------------------------------
template<int D>
__global__ __launch_bounds__(THREADS)
void agg_q_kernel(const short* __restrict__ tq, const float* __restrict__ qscale,
                  const int* __restrict__ row_ptr, const int* __restrict__ col,
                  const float* __restrict__ norm_dst, const float* __restrict__ bias,
                  float* __restrict__ out, int N) {
    constexpr int TPN = D / 8;
    constexpr int NPB = THREADS / TPN;
    const int tid  = threadIdx.x;
    const int ln   = tid % TPN;
    const int g    = tid / TPN;
    const int node = blockIdx.x * NPB + g;
    if (node >= N) return;

    const int beg = row_ptr[node];
    const int end = row_ptr[node + 1];

    float acc[8];
#pragma unroll
    for (int c = 0; c < 8; ++c) acc[c] = 0.f;

    int j = beg;
    for (; j + 3 < end; j += 4) {
        int s0 = col[j], s1 = col[j + 1], s2 = col[j + 2], s3 = col[j + 3];
        short8_t v0 = *(const short8_t*)&tq[(size_t)s0 * D + ln * 8];
        short8_t v1 = *(const short8_t*)&tq[(size_t)s1 * D + ln * 8];
        short8_t v2 = *(const short8_t*)&tq[(size_t)s2 * D + ln * 8];
        short8_t v3 = *(const short8_t*)&tq[(size_t)s3 * D + ln * 8];
        float c0 = qscale[s0], c1 = qscale[s1], c2 = qscale[s2], c3 = qscale[s3];
#pragma unroll
        for (int c = 0; c < 8; ++c)
            acc[c] += (float)v0[c] * c0 + (float)v1[c] * c1
                    + (float)v2[c] * c2 + (float)v3[c] * c3;
    }
    for (; j < end; ++j) {
        int s0 = col[j];
        short8_t v0 = *(const short8_t*)&tq[(size_t)s0 * D + ln * 8];
        float c0 = qscale[s0];
#pragma unroll
        for (int c = 0; c < 8; ++c) acc[c] += (float)v0[c] * c0;
    }

    float nd = norm_dst[node];
    float4 b0 = *(const float4*)&bias[ln * 8];
    float4 b1 = *(const float4*)&bias[ln * 8 + 4];
    float4 o0, o1;
    o0.x = fmaxf(acc[0] * nd + b0.x, 0.f);
    o0.y = fmaxf(acc[1] * nd + b0.y, 0.f);
    o0.z = fmaxf(acc[2] * nd + b0.z, 0.f);
    o0.w = fmaxf(acc[3] * nd + b0.w, 0.f);
    o1.x = fmaxf(acc[4] * nd + b1.x, 0.f);
    o1.y = fmaxf(acc[5] * nd + b1.y, 0.f);
    o1.z = fmaxf(acc[6] * nd + b1.z, 0.f);
    o1.w = fmaxf(acc[7] * nd + b1.w, 0.f);
    *(float4*)&out[(size_t)node * D + ln * 8] = o0;
    *(float4*)&out[(size_t)node * D + ln * 8 + 4] = o1;
}

// ---------------------------------------------------------------------------
// Fused agg_l + gemm_{l+1} for SMALL layers (LDS < 27KB).
// ---------------------------------------------------------------------------
template<int DIN, int NOUT>
__global__ __launch_bounds__(THREADS)
void fused_agg_gemm_kernel(const short* __restrict__ tq_in, const float* __restrict__ qs_in,
                           const int* __restrict__ row_ptr, const int* __restrict__ col,
                           const float* __restrict__ norm_dst, const float* __restrict__ bias,
                           const short* __restrict__ wt_hi, const short* __restrict__ wt_lo,
                           const float* __restrict__ norm_src,
                           short* __restrict__ tq_out, float* __restrict__ qs_out, int N) {
    constexpr int Kp   = (DIN + 31) & ~31;
    constexpr int STR  = Kp + 8;
    constexpr int DINP = DIN + 4;
    constexpr int TPN  = DIN / 8;

    __shared__ float As[64 * DINP];
    __shared__ short lh[NOUT * STR];
    __shared__ short ll[NOUT * STR];

    const int tid = threadIdx.x;
    {
        constexpr int CNT = NOUT * STR / 2;
        const int* gh = (const int*)wt_hi;
        const int* gl = (const int*)wt_lo;
        int* sh = (int*)lh;
        int* sl = (int*)ll;
        for (int i = tid; i < CNT; i += THREADS) { sh[i] = gh[i]; sl[i] = gl[i]; }
    }

    const int ln = tid % TPN;
    for (int n0 = tid / TPN; n0 < 64; n0 += THREADS / TPN) {
        const int node = blockIdx.x * 64 + n0;
        if (node < N) {
            const int beg = row_ptr[node];
            const int end = row_ptr[node + 1];
            float acc[8];
#pragma unroll
            for (int c = 0; c < 8; ++c) acc[c] = 0.f;
            int j = beg;
            for (; j + 3 < end; j += 4) {
                int s0 = col[j], s1 = col[j + 1], s2 = col[j + 2], s3 = col[j + 3];
                short8_t v0 = *(const short8_t*)&tq_in[(size_t)s0 * DIN + ln * 8];
                short8_t v1 = *(const short8_t*)&tq_in[(size_t)s1 * DIN + ln * 8];
                short8_t v2 = *(const short8_t*)&tq_in[(size_t)s2 * DIN + ln * 8];
                short8_t v3 = *(const short8_t*)&tq_in[(size_t)s3 * DIN + ln * 8];
                float c0 = qs_in[s0], c1 = qs_in[s1], c2 = qs_in[s2], c3 = qs_in[s3];
#pragma unroll
                for (int c = 0; c < 8; ++c)
                    acc[c] += (float)v0[c] * c0 + (float)v1[c] * c1
                            + (float)v2[c] * c2 + (float)v3[c] * c3;
            }
            for (; j < end; ++j) {
                int s0 = col[j];
                short8_t v0 = *(const short8_t*)&tq_in[(size_t)s0 * DIN + ln * 8];
                float c0 = qs_in[s0];
#pragma unroll
                for (int c = 0; c < 8; ++c) acc[c] += (float)v0[c] * c0;
            }
            float nd = norm_dst[node];
#pragma unroll
            for (int c = 0; c < 8; ++c)
                As[n0 * DINP + ln * 8 + c] = fmaxf(acc[c] * nd + bias[ln * 8 + c], 0.f);
        }
    }
    __syncthreads();

    gemm_core_lds<DIN, NOUT, DINP>(As, lh, ll, norm_src, tq_out, qs_out, N, blockIdx.x, tid);
}

extern "C" void kernel_launch(void* const* d_in, const int* in_sizes, int n_in,
                              void* d_out, int out_size, void* d_ws, size_t ws_size,
                              hipStream_t stream) {
    const float* x     = (const float*)d_in[0];
    const int*   edges = (const int*)d_in[1];
    const float* W1 = (const float*)d_in[2];  const float* b1 = (const float*)d_in[3];
    const float* W2 = (const float*)d_in[4];  const float* b2 = (const float*)d_in[5];
    const float* W3 = (const float*)d_in[6];  const float* b3 = (const float*)d_in[7];
    const float* W4 = (const float*)d_in[8];  const float* b4 = (const float*)d_in[9];
    const float* W5 = (const float*)d_in[10]; const float* b5 = (const float*)d_in[11];

    const int N = in_sizes[0] / 128;   // 50000
    const int E = in_sizes[1] / 2;     // 800000
    const int* src = edges;
    const int* dst = edges + E;

    // ---- carve workspace ----
    char* ws = (char*)d_ws;
    size_t off = 0;
    auto carve = [&](size_t bytes) -> void* {
        void* p = ws + off;
        off += (bytes + 255) & ~(size_t)255;
        return p;
    };
    short* tqA      = (short*)carve((size_t)N * 128 * 2);   // L1 out (128) / L2 out (64) / L4 out (16)
    short* tqB      = (short*)carve((size_t)N * 64 * 2);    // L3 out (32) / L5 out (16)
    short* tqH      = (short*)carve((size_t)N * 128 * 2);   // agg1 out (int16, 128)
    float* norm_src = (float*)carve((size_t)N * 4);
    float* norm_dst = (float*)carve((size_t)N * 4);
    int*   row_ptr  = (int*)carve((size_t)(N + 1) * 4);
    int*   col      = (int*)carve((size_t)E * 4);
    float* qsA      = (float*)carve((size_t)2 * N * 4);     // L1 per-half; stride-1 reuse
    float* qsB      = (float*)carve((size_t)N * 4);
    float* qsH      = (float*)carve((size_t)N * 4);         // agg1 per-node scale
    int*   flags    = (int*)carve((size_t)256 * 4);
    short* wts      = (short*)carve((size_t)24576 * 2);
    unsigned* p_src = (unsigned*)carve((size_t)HIST_B * HWORDS * 4);   // 6.4 MB
    unsigned* p_dst = (unsigned*)carve((size_t)HIST_B * HWORDS * 4);   // 6.4 MB
    unsigned char* rank = (unsigned char*)carve((size_t)E);            // 0.8 MB
    (void)ws_size;

    short* w2h = wts;            short* w2l = w2h + 8704;
    short* w3h = w2l + 8704;     short* w3l = w3h + 2304;
    short* w4h = w3l + 2304;     short* w4l = w4h + 640;
    short* w5h = w4l + 640;      short* w5l = w5h + 640;   // end 24576

    const int chunk = (E + HIST_B - 1) / HIST_B;   // 6250
    const int gridG = (N + 63) / 64;               // 782

    // 1) packed front: gemm1 (both halves) || hist || W2-5 split + flag zero
    packed0_kernel<<<G1BLKS + 2 * HIST_B + 49, THREADS, 0, stream>>>(
        x, W1, W2, W3, W4, W5, tqA, qsA, src, dst, p_src, p_dst, rank, flags,
        w2h, w2l, w3h, w3l, w4h, w4l, w5h, w5l, E, chunk, N);

    // 2) reduce + full scan (4-way chunk split + lookback)
    reduce_scan_kernel<<<RS_BLOCKS, THREADS, 0, stream>>>(
        p_src, p_dst, norm_src, norm_dst, qsA, row_ptr, flags, N);

    // 3) scatter -> col (512 quarter-chunk blocks)
    scatter_kernel<<<4 * HIST_B, THREADS, 0, stream>>>(src, dst, rank, row_ptr, p_dst, col, E, chunk);

    // 4) agg1: edge-parallel x2, int16+scale output
    agg1_q_kernel<<<(N + 7) / 8, THREADS, 0, stream>>>(
        tqA, qsA, row_ptr, col, norm_dst, b1, tqH, qsH, N);

    // 5) gemm2: int16 A, row scale folded
    gemm_mfma_q_kernel<128, 64><<<gridG, THREADS, 0, stream>>>(
        tqH, qsH, w2h, w2l, norm_src, tqA, qsA, N);

    // 6-8) fused small layers
    fused_agg_gemm_kernel<64, 32><<<gridG, THREADS, 0, stream>>>(
        tqA, qsA, row_ptr, col, norm_dst, b2, w3h, w3l, norm_src, tqB, qsB, N);
    fused_agg_gemm_kernel<32, 16><<<gridG, THREADS, 0, stream>>>(
        tqB, qsB, row_ptr, col, norm_dst, b3, w4h, w4l, norm_src, tqA, qsA, N);
    fused_agg_gemm_kernel<16, 16><<<gridG, THREADS, 0, stream>>>(
        tqA, qsA, row_ptr, col, norm_dst, b4, w5h, w5l, norm_src, tqB, qsB, N);

    // 9) final aggregate -> d_out
    agg_q_kernel<16><<<(N + 127) / 128, THREADS, 0, stream>>>(
        tqB, qsB, row_ptr, col, norm_dst, b5, (float*)d_out, N);
}

// Round 15
// 259.091 us; speedup vs baseline: 1.1219x; 1.0015x over previous
//
#include <hip/hip_runtime.h>
#include <hip/hip_bf16.h>

// ---------------------------------------------------------------------------
// GCN: 5 layers of  h = relu( norm_dst * scatter_add( (h@W * norm_src)[src] ) + b )
// R15: agg1 edge-parallelism x2 -> x4 (full 64-lane wave per node: 16 col
// lanes x 4 edge parities, shfl_xor(16)+shfl_xor(32) combine). Serial
// dependent-load depth per node 8 -> 4; ~4x outstanding misses on the
// latency-bound replicated gather. Isolated change vs R14.
// ---------------------------------------------------------------------------

#define THREADS 256
#define HIST_B 128          // edge chunks; hist uses 2*HIST_B blocks
#define HWORDS 12500        // u32 words, 4 nodes/word (8-bit counts), N=50000
#define RS_BLOCKS 196       // ceil(HWORDS/64)
#define G1BLKS 782          // ceil(50000/64): gemm1 blocks (both halves each)
#define C4 (HIST_B / 4)     // chunks per quarter in reduce_scan (32)

typedef __attribute__((ext_vector_type(8))) short short8_t;
typedef __attribute__((ext_vector_type(4))) float float4_t;

__device__ __forceinline__ unsigned short f2bf_rne(float f) {
    unsigned u = __builtin_bit_cast(unsigned, f);
    unsigned r = u + 0x7fffu + ((u >> 16) & 1u);
    return (unsigned short)(r >> 16);
}
__device__ __forceinline__ float bf2f(unsigned short h) {
    return __builtin_bit_cast(float, ((unsigned)h) << 16);
}

// ---------------------------------------------------------------------------
// Split-bf16 MFMA quant epilogue (D: col=lane&15, row=quad*4+reg).
// ASCALE: extra per-row input scale (int16-A dequant) multiplied into s.
// ---------------------------------------------------------------------------
template<int NT, bool NORM, bool ASCALE>
__device__ __forceinline__ void quant_epilogue(float4_t* acc, const float* __restrict__ norm,
                                               const float* __restrict__ ascale,
                                               short* __restrict__ outq, float* __restrict__ qscale,
                                               int M, int blk, int tid,
                                               int ostride, int ocol0, int qstride, int qoff) {
    const int w    = tid >> 6;
    const int lane = tid & 63;
    const int ln   = lane & 15;
    const int quad = lane >> 4;
    const int orow = blk * 64 + w * 16 + quad * 4;
#pragma unroll
    for (int i = 0; i < 4; ++i) {
        int r = orow + i;
        float m = 0.f;
#pragma unroll
        for (int nt = 0; nt < NT; ++nt) m = fmaxf(m, fabsf(acc[nt][i]));
#pragma unroll
        for (int off = 1; off < 16; off <<= 1) m = fmaxf(m, __shfl_xor(m, off));
        float s = 1.f;
        if (NORM) s = (r < M) ? norm[r] : 0.f;
        if (ASCALE && r < M) s *= ascale[r];
        float rowmax = m * s;
        float inv = (rowmax > 0.f) ? (32767.f / rowmax) : 0.f;
        if (r < M) {
            if (ln == 0) qscale[r * qstride + qoff] = rowmax * (1.f / 32767.f);
#pragma unroll
            for (int nt = 0; nt < NT; ++nt)
                outq[(size_t)r * ostride + ocol0 + nt * 16 + ln] =
                    (short)(int)__builtin_rintf(acc[nt][i] * s * inv);
        }
    }
}

// MFMA core, A int16 from global (row-major, width K) + per-row scale folded
// into epilogue. Split-bf16 of int16 is exact (remainder <= 64).
template<int K, int NOUT>
__device__ __forceinline__ void gemm_core_q(const short* __restrict__ Aq,
                                            const float* __restrict__ ascale,
                                            const short* lh, const short* ll,
                                            const float* __restrict__ norm,
                                            short* __restrict__ outq, float* __restrict__ qscale,
                                            int M, int blk, int tid) {
    constexpr int Kp  = (K + 31) & ~31;
    constexpr int STR = Kp + 8;
    constexpr int NT  = NOUT / 16;
    const int w    = tid >> 6;
    const int lane = tid & 63;
    const int ln   = lane & 15;
    const int quad = lane >> 4;
    const int row  = blk * 64 + w * 16 + ln;
    const bool rv  = row < M;

    float4_t acc[NT];
#pragma unroll
    for (int i = 0; i < NT; ++i) acc[i] = (float4_t){0.f, 0.f, 0.f, 0.f};

#pragma unroll
    for (int kt = 0; kt < Kp / 32; ++kt) {
        const int k0 = kt * 32 + quad * 8;
        short8_t qv = (short8_t)(short)0;
        if (rv && k0 < K) qv = *(const short8_t*)&Aq[(size_t)row * K + k0];
        short8_t ahi, alo;
#pragma unroll
        for (int j = 0; j < 8; ++j) {
            float a = (float)qv[j];
            unsigned short h = f2bf_rne(a);
            ahi[j] = (short)h;
            alo[j] = (short)f2bf_rne(a - bf2f(h));
        }
#pragma unroll
        for (int nt = 0; nt < NT; ++nt) {
            const int bidx = (nt * 16 + ln) * STR + kt * 32 + quad * 8;
            short8_t bh = *(const short8_t*)&lh[bidx];
            short8_t bl = *(const short8_t*)&ll[bidx];
            acc[nt] = __builtin_amdgcn_mfma_f32_16x16x32_bf16(ahi, bh, acc[nt], 0, 0, 0);
            acc[nt] = __builtin_amdgcn_mfma_f32_16x16x32_bf16(ahi, bl, acc[nt], 0, 0, 0);
            acc[nt] = __builtin_amdgcn_mfma_f32_16x16x32_bf16(alo, bh, acc[nt], 0, 0, 0);
        }
    }
    quant_epilogue<NT, true, true>(acc, norm, ascale, outq, qscale, M, blk, tid,
                                   NOUT, 0, 1, 0);
}

// MFMA core, A fp32 from LDS (stride DINP floats, 64 local rows).
template<int K, int NOUT, int DINP>
__device__ __forceinline__ void gemm_core_lds(const float* As,
                                              const short* lh, const short* ll,
                                              const float* __restrict__ norm,
                                              short* __restrict__ outq, float* __restrict__ qscale,
                                              int M, int blk, int tid) {
    constexpr int Kp  = (K + 31) & ~31;
    constexpr int STR = Kp + 8;
    constexpr int NT  = NOUT / 16;
    const int w    = tid >> 6;
    const int lane = tid & 63;
    const int ln   = lane & 15;
    const int quad = lane >> 4;
    const int rloc = w * 16 + ln;
    const bool rv  = (blk * 64 + rloc) < M;

    float4_t acc[NT];
#pragma unroll
    for (int i = 0; i < NT; ++i) acc[i] = (float4_t){0.f, 0.f, 0.f, 0.f};

#pragma unroll
    for (int kt = 0; kt < Kp / 32; ++kt) {
        const int k0 = kt * 32 + quad * 8;
        float a[8];
        if (rv && k0 < K) {
            float4 v0 = *(const float4*)&As[rloc * DINP + k0];
            float4 v1 = *(const float4*)&As[rloc * DINP + k0 + 4];
            a[0] = v0.x; a[1] = v0.y; a[2] = v0.z; a[3] = v0.w;
            a[4] = v1.x; a[5] = v1.y; a[6] = v1.z; a[7] = v1.w;
        } else {
#pragma unroll
            for (int j = 0; j < 8; ++j) a[j] = 0.f;
        }
        short8_t ahi, alo;
#pragma unroll
        for (int j = 0; j < 8; ++j) {
            unsigned short h = f2bf_rne(a[j]);
            ahi[j] = (short)h;
            alo[j] = (short)f2bf_rne(a[j] - bf2f(h));
        }
#pragma unroll
        for (int nt = 0; nt < NT; ++nt) {
            const int bidx = (nt * 16 + ln) * STR + kt * 32 + quad * 8;
            short8_t bh = *(const short8_t*)&lh[bidx];
            short8_t bl = *(const short8_t*)&ll[bidx];
            acc[nt] = __builtin_amdgcn_mfma_f32_16x16x32_bf16(ahi, bh, acc[nt], 0, 0, 0);
            acc[nt] = __builtin_amdgcn_mfma_f32_16x16x32_bf16(ahi, bl, acc[nt], 0, 0, 0);
            acc[nt] = __builtin_amdgcn_mfma_f32_16x16x32_bf16(alo, bh, acc[nt], 0, 0, 0);
        }
    }
    quant_epilogue<NT, true, false>(acc, norm, nullptr, outq, qscale, M, blk, tid,
                                    NOUT, 0, 1, 0);
}

// W pre-split element: W (KxNOUT fp32) -> W^T hi/lo bf16 [NOUT][STR shorts].
__device__ __forceinline__ void conv_one(const float* __restrict__ W, short* __restrict__ hi,
                                         short* __restrict__ lo, int K, int NOUT, int STR, int i) {
    int n = i / STR;
    int kk = i % STR;
    float v = (kk < K) ? W[(size_t)kk * NOUT + n] : 0.f;
    unsigned short h = f2bf_rne(v);
    hi[i] = (short)h;
    lo[i] = (short)f2bf_rne(v - bf2f(h));
}

// ---------------------------------------------------------------------------
// packed0: gemm1 (both W1 halves per block) || hist || W2-5 split + flag zero.
// Static LDS 50,048 B -> 3 blocks/CU.
// ---------------------------------------------------------------------------
__global__ __launch_bounds__(THREADS)
void packed0_kernel(const float* __restrict__ x, const float* __restrict__ W1,
                    const float* __restrict__ W2, const float* __restrict__ W3,
                    const float* __restrict__ W4, const float* __restrict__ W5,
                    short* __restrict__ tq, float* __restrict__ qscale2,
                    const int* __restrict__ src, const int* __restrict__ dst,
                    unsigned* __restrict__ p_src, unsigned* __restrict__ p_dst,
                    unsigned char* __restrict__ rank, int* __restrict__ flags,
                    short* w2h, short* w2l, short* w3h, short* w3l,
                    short* w4h, short* w4l, short* w5h, short* w5l,
                    int E, int chunk, int N) {
    __shared__ __align__(16) char smem[50048];
    const int blk = blockIdx.x;
    const int t = threadIdx.x;

    if (blk < G1BLKS) {
        short* lh = (short*)smem;           // 64*136 = 8704 shorts
        short* ll = (short*)smem + 8704;

        const int lane = t & 63;
        const int ln   = lane & 15;
        const int quad = lane >> 4;
        const int row  = blk * 64 + (t >> 6) * 16 + ln;
        const bool rv  = row < N;

        short8_t ahi[4], alo[4];
#pragma unroll
        for (int kt = 0; kt < 4; ++kt) {
            const int k0 = kt * 32 + quad * 8;
            float a[8];
            if (rv) {
                float4 v0 = *(const float4*)&x[(size_t)row * 128 + k0];
                float4 v1 = *(const float4*)&x[(size_t)row * 128 + k0 + 4];
                a[0] = v0.x; a[1] = v0.y; a[2] = v0.z; a[3] = v0.w;
                a[4] = v1.x; a[5] = v1.y; a[6] = v1.z; a[7] = v1.w;
            } else {
#pragma unroll
                for (int j = 0; j < 8; ++j) a[j] = 0.f;
            }
#pragma unroll
            for (int j = 0; j < 8; ++j) {
                unsigned short h = f2bf_rne(a[j]);
                ahi[kt][j] = (short)h;
                alo[kt][j] = (short)f2bf_rne(a[j] - bf2f(h));
            }
        }

        for (int h = 0; h < 2; ++h) {
            for (int j = t; j < 128 * 64; j += THREADS) {
                int kk = j >> 6, n = j & 63;
                float v = W1[kk * 128 + h * 64 + n];
                unsigned short hh = f2bf_rne(v);
                lh[n * 136 + kk] = (short)hh;
                ll[n * 136 + kk] = (short)f2bf_rne(v - bf2f(hh));
            }
            __syncthreads();

            float4_t acc[4];
#pragma unroll
            for (int i = 0; i < 4; ++i) acc[i] = (float4_t){0.f, 0.f, 0.f, 0.f};
#pragma unroll
            for (int kt = 0; kt < 4; ++kt) {
#pragma unroll
                for (int nt = 0; nt < 4; ++nt) {
                    const int bidx = (nt * 16 + ln) * 136 + kt * 32 + quad * 8;
                    short8_t bh = *(const short8_t*)&lh[bidx];
                    short8_t bl = *(const short8_t*)&ll[bidx];
                    acc[nt] = __builtin_amdgcn_mfma_f32_16x16x32_bf16(ahi[kt], bh, acc[nt], 0, 0, 0);
                    acc[nt] = __builtin_amdgcn_mfma_f32_16x16x32_bf16(ahi[kt], bl, acc[nt], 0, 0, 0);
                    acc[nt] = __builtin_amdgcn_mfma_f32_16x16x32_bf16(alo[kt], bh, acc[nt], 0, 0, 0);
                }
            }
            quant_epilogue<4, false, false>(acc, nullptr, nullptr, tq, qscale2, N, blk, t,
                                            128, h * 64, 2, h);
            if (h == 0) __syncthreads();   // LDS reuse barrier before half 1 staging
        }
    } else if (blk < G1BLKS + 2 * HIST_B) {
        unsigned* bins = (unsigned*)smem;   // 50 KB
        const int hb = blk - G1BLKS;
        const bool is_dst = hb < HIST_B;
        const int b = is_dst ? hb : hb - HIST_B;
        const int e0 = b * chunk;
        int e1 = e0 + chunk; if (e1 > E) e1 = E;
        const int* __restrict__ idx = is_dst ? dst : src;
        unsigned* __restrict__ pout = is_dst ? p_dst : p_src;

        for (int w = t; w < HWORDS; w += THREADS) bins[w] = 0;
        __syncthreads();
        for (int e = e0 + t; e < e1; e += THREADS) {
            int d = idx[e];
            unsigned sh = (unsigned)(d & 3) * 8u;
            unsigned old = atomicAdd(&bins[d >> 2], 1u << sh);
            if (is_dst) rank[e] = (unsigned char)((old >> sh) & 0xffu);
        }
        __syncthreads();
        for (int w = t; w < HWORDS; w += THREADS)
            pout[(size_t)b * HWORDS + w] = bins[w];
    } else {
        int cb = blk - G1BLKS - 2 * HIST_B;     // 0..48
        if (cb == 48) {
            flags[t] = 0;
            return;
        }
        int i = cb * THREADS + t;
        if (i < 8704)                        conv_one(W2, w2h, w2l, 128, 64, 136, i);
        else if ((i -= 8704) < 2304)         conv_one(W3, w3h, w3l, 64, 32, 72, i);
        else if ((i -= 2304) < 640)          conv_one(W4, w4h, w4l, 32, 16, 40, i);
        else { i -= 640;                     conv_one(W5, w5h, w5l, 16, 16, 40, i); }
    }
}

// ---------------------------------------------------------------------------
// reduce_scan: 196 blocks, 64 words/block, 4 chunk-quarters (32 chunks each);
// decoupled lookback -> row_ptr; folds norm_src into L1 per-half scales.
// ---------------------------------------------------------------------------
__global__ __launch_bounds__(THREADS)
void reduce_scan_kernel(const unsigned* __restrict__ p_src, unsigned* __restrict__ p_dst,
                        float* __restrict__ norm_src, float* __restrict__ norm_dst,
                        float* __restrict__ qscale2, int* __restrict__ row_ptr,
                        int* __restrict__ flags, int N) {
    __shared__ unsigned qd[4][64];
    __shared__ unsigned qs[4][64];
    __shared__ int sscan[64];
    __shared__ int bexcl_sh;
    const int t  = threadIdx.x;
    const int b  = blockIdx.x;
    const int q  = t >> 6;
    const int wl = t & 63;
    const int w  = b * 64 + wl;
    const bool wv = (w < HWORDS);

    unsigned vals[C4];
    unsigned dsum = 0, ssum = 0;
    if (wv) {
#pragma unroll
        for (int i = 0; i < C4; ++i) {
            int c = q * C4 + i;
            vals[i] = p_dst[(size_t)c * HWORDS + w];
            dsum += vals[i];
        }
#pragma unroll
        for (int i = 0; i < C4; ++i) {
            int c = q * C4 + i;
            ssum += p_src[(size_t)c * HWORDS + w];
        }
    }
    qd[q][wl] = dsum;
    qs[q][wl] = ssum;
    __syncthreads();

    unsigned off = 0, dfull = 0, sfull = 0;
#pragma unroll
    for (int qq = 0; qq < 4; ++qq) {
        unsigned v = qd[qq][wl];
        if (qq < q) off += v;
        dfull += v;
        sfull += qs[qq][wl];
    }

    if (wv) {
        unsigned run = off;
#pragma unroll
        for (int i = 0; i < C4; ++i) {
            int c = q * C4 + i;
            p_dst[(size_t)c * HWORDS + w] = run;
            run += vals[i];
        }
    }

    int d0 = 0, d1 = 0, d2 = 0, d3 = 0, wdeg = 0;
    if (q == 0) {
        d0 = (int)(dfull & 0xffu); d1 = (int)((dfull >> 8) & 0xffu);
        d2 = (int)((dfull >> 16) & 0xffu); d3 = (int)(dfull >> 24);
        wdeg = d0 + d1 + d2 + d3;
        if (wv) {
#pragma unroll
            for (int l = 0; l < 4; ++l) {
                int node = 4 * w + l;
                int dd = (l == 0) ? d0 : (l == 1) ? d1 : (l == 2) ? d2 : d3;
                int ds = (int)((sfull >> (8 * l)) & 0xffu);
                norm_dst[node] = rsqrtf((float)(dd < 1 ? 1 : dd));
                float ns = rsqrtf((float)(ds < 1 ? 1 : ds));
                norm_src[node] = ns;
                qscale2[2 * node]     *= ns;
                qscale2[2 * node + 1] *= ns;
            }
        }
        sscan[wl] = wv ? wdeg : 0;
    }
    __syncthreads();
    for (int o = 1; o < 64; o <<= 1) {
        int u = 0;
        if (t < 64 && t >= o) u = sscan[t - o];
        __syncthreads();
        if (t < 64) sscan[t] += u;
        __syncthreads();
    }
    const int btotal = sscan[63];

    if (t == 0) atomicExch(&flags[b], btotal + 1);
    if (t < 64) {
        int v = 0;
        for (int p = t; p < b; p += 64) {
            int f;
            do { f = atomicAdd(&flags[p], 0); } while (f == 0);
            v += f - 1;
        }
#pragma unroll
        for (int o = 1; o < 64; o <<= 1) v += __shfl_xor(v, o);
        if (t == 0) bexcl_sh = v;
    }
    __syncthreads();

    if (q == 0 && wv) {
        int pre = bexcl_sh + sscan[wl] - wdeg;
        int n0 = 4 * w;
        row_ptr[n0 + 0] = pre; pre += d0;
        row_ptr[n0 + 1] = pre; pre += d1;
        row_ptr[n0 + 2] = pre; pre += d2;
        row_ptr[n0 + 3] = pre;
    }
    if (b == RS_BLOCKS - 1 && t == 0) row_ptr[N] = bexcl_sh + btotal;
}

// ---------------------------------------------------------------------------
// scatter: 512 quarter-chunk blocks, precomputed rank bytes.
// ---------------------------------------------------------------------------
__global__ __launch_bounds__(THREADS)
void scatter_kernel(const int* __restrict__ src, const int* __restrict__ dst,
                    const unsigned char* __restrict__ rank,
                    const int* __restrict__ row_ptr, const unsigned* __restrict__ p_dst,
                    int* __restrict__ col, int E, int chunk) {
    const int bc  = blockIdx.x >> 2;
    const int sub = blockIdx.x & 3;
    const int qch = (chunk + 3) >> 2;
    const int e0 = bc * chunk;
    int e1 = e0 + chunk; if (e1 > E) e1 = E;
    int s = e0 + sub * qch;
    int send = s + qch; if (send > e1) send = e1;
    for (int e = s + threadIdx.x; e < send; e += THREADS) {
        int d = dst[e];
        unsigned sh = (unsigned)(d & 3) * 8u;
        unsigned pre = (p_dst[(size_t)bc * HWORDS + (d >> 2)] >> sh) & 0xffu;
        col[row_ptr[d] + (int)pre + (int)rank[e]] = src[e];
    }
}

// ---------------------------------------------------------------------------
// agg1: int16 gather with QS2 input scales, edge-parallel x4 (64 lanes/node:
// 16 col lanes x 4 edge parities), int16 + per-node scale OUTPUT. 4 nodes/blk.
// ---------------------------------------------------------------------------
__global__ __launch_bounds__(THREADS)
void agg1_q_kernel(const short* __restrict__ tq, const float* __restrict__ qscale2,
                   const int* __restrict__ row_ptr, const int* __restrict__ col,
                   const float* __restrict__ norm_dst, const float* __restrict__ bias,
                   short* __restrict__ outq, float* __restrict__ qs_out, int N) {
    const int tid  = threadIdx.x;
    const int ln   = tid & 15;          // col lane: cols [ln*8, ln*8+8)
    const int ep   = (tid >> 4) & 3;    // edge parity (0..3)
    const int g    = tid >> 6;          // node within block (0..3)
    const int node = blockIdx.x * 4 + g;
    if (node >= N) return;

    const int half = ln >> 3;
    const int beg = row_ptr[node];
    const int end = row_ptr[node + 1];

    float acc[8];
#pragma unroll
    for (int c = 0; c < 8; ++c) acc[c] = 0.f;

    int j = beg + ep;
    for (; j + 4 < end; j += 8) {
        int s0 = col[j];
        int s1 = col[j + 4];
        short8_t v0 = *(const short8_t*)&tq[(size_t)s0 * 128 + ln * 8];
        short8_t v1 = *(const short8_t*)&tq[(size_t)s1 * 128 + ln * 8];
        float c0 = qscale2[2 * s0 + half];
        float c1 = qscale2[2 * s1 + half];
#pragma unroll
        for (int c = 0; c < 8; ++c)
            acc[c] += (float)v0[c] * c0 + (float)v1[c] * c1;
    }
    if (j < end) {
        int s0 = col[j];
        short8_t v0 = *(const short8_t*)&tq[(size_t)s0 * 128 + ln * 8];
        float c0 = qscale2[2 * s0 + half];
#pragma unroll
        for (int c = 0; c < 8; ++c) acc[c] += (float)v0[c] * c0;
    }

    // combine 4 edge parities (lanes differ in bits 4-5)
#pragma unroll
    for (int c = 0; c < 8; ++c) {
        acc[c] += __shfl_xor(acc[c], 16);
        acc[c] += __shfl_xor(acc[c], 32);
    }

    float nd = norm_dst[node];
    float vals[8];
    float m = 0.f;
#pragma unroll
    for (int c = 0; c < 8; ++c) {
        vals[c] = fmaxf(acc[c] * nd + bias[ln * 8 + c], 0.f);
        m = fmaxf(m, vals[c]);
    }
#pragma unroll
    for (int off = 1; off < 16; off <<= 1) m = fmaxf(m, __shfl_xor(m, off));
    float inv = (m > 0.f) ? (32767.f / m) : 0.f;

    if (ep == 0) {
        short8_t q;
#pragma unroll
        for (int c = 0; c < 8; ++c) q[c] = (short)(int)__builtin_rintf(vals[c] * inv);
        *(short8_t*)&outq[(size_t)node * 128 + ln * 8] = q;
        if (ln == 0) qs_out[node] = m * (1.f / 32767.f);
    }
}

// ---------------------------------------------------------------------------
// gemm2: int16 A (exact split-bf16) + per-row scale folded into epilogue.
// ---------------------------------------------------------------------------
template<int K, int NOUT>
__global__ __launch_bounds__(THREADS)
void gemm_mfma_q_kernel(const short* __restrict__ Aq, const float* __restrict__ ascale,
                        const short* __restrict__ wt_hi, const short* __restrict__ wt_lo,
                        const float* __restrict__ norm,
                        short* __restrict__ outq, float* __restrict__ qscale, int M) {
    constexpr int Kp  = (K + 31) & ~31;
    constexpr int STR = Kp + 8;

    __shared__ short lh[NOUT * STR];
    __shared__ short ll[NOUT * STR];

    const int tid = threadIdx.x;
    {
        constexpr int CNT = NOUT * STR / 2;
        const int* gh = (const int*)wt_hi;
        const int* gl = (const int*)wt_lo;
        int* sh = (int*)lh;
        int* sl = (int*)ll;
        for (int i = tid; i < CNT; i += THREADS) { sh[i] = gh[i]; sl[i] = gl[i]; }
    }
    __syncthreads();
    gemm_core_q<K, NOUT>(Aq, ascale, lh, ll, norm, outq, qscale, M, blockIdx.x, tid);
}

// ---------------------------------------------------------------------------
// Standalone int16 CSR aggregate (unroll-4), fp32 out (final layer).
// ---------------------------------------------------------------------------
template<int D>
__global__ __launch_bounds__(THREADS)
void agg_q_kernel(const short* __restrict__ tq, const float* __restrict__ qscale,
                  const int* __restrict__ row_ptr, const int* __restrict__ col,
                  const float* __restrict__ norm_dst, const float* __restrict__ bias,
                  float* __restrict__ out, int N) {
    constexpr int TPN = D / 8;
    constexpr int NPB = THREADS / TPN;
    const int tid  = threadIdx.x;
    const int ln   = tid % TPN;
    const int g    = tid / TPN;
    const int node = blockIdx.x * NPB + g;
    if (node >= N) return;

    const int beg = row_ptr[node];
    const int end = row_ptr[node + 1];

    float acc[8];
#pragma unroll
    for (int c = 0; c < 8; ++c) acc[c] = 0.f;

    int j = beg;
    for (; j + 3 < end; j += 4) {
        int s0 = col[j], s1 = col[j + 1], s2 = col[j + 2], s3 = col[j + 3];
        short8_t v0 = *(const short8_t*)&tq[(size_t)s0 * D + ln * 8];
        short8_t v1 = *(const short8_t*)&tq[(size_t)s1 * D + ln * 8];
        short8_t v2 = *(const short8_t*)&tq[(size_t)s2 * D + ln * 8];
        short8_t v3 = *(const short8_t*)&tq[(size_t)s3 * D + ln * 8];
        float c0 = qscale[s0], c1 = qscale[s1], c2 = qscale[s2], c3 = qscale[s3];
#pragma unroll
        for (int c = 0; c < 8; ++c)
            acc[c] += (float)v0[c] * c0 + (float)v1[c] * c1
                    + (float)v2[c] * c2 + (float)v3[c] * c3;
    }
    for (; j < end; ++j) {
        int s0 = col[j];
        short8_t v0 = *(const short8_t*)&tq[(size_t)s0 * D + ln * 8];
        float c0 = qscale[s0];
#pragma unroll
        for (int c = 0; c < 8; ++c) acc[c] += (float)v0[c] * c0;
    }

    float nd = norm_dst[node];
    float4 b0 = *(const float4*)&bias[ln * 8];
    float4 b1 = *(const float4*)&bias[ln * 8 + 4];
    float4 o0, o1;
    o0.x = fmaxf(acc[0] * nd + b0.x, 0.f);
    o0.y = fmaxf(acc[1] * nd + b0.y, 0.f);
    o0.z = fmaxf(acc[2] * nd + b0.z, 0.f);
    o0.w = fmaxf(acc[3] * nd + b0.w, 0.f);
    o1.x = fmaxf(acc[4] * nd + b1.x, 0.f);
    o1.y = fmaxf(acc[5] * nd + b1.y, 0.f);
    o1.z = fmaxf(acc[6] * nd + b1.z, 0.f);
    o1.w = fmaxf(acc[7] * nd + b1.w, 0.f);
    *(float4*)&out[(size_t)node * D + ln * 8] = o0;
    *(float4*)&out[(size_t)node * D + ln * 8 + 4] = o1;
}

// ---------------------------------------------------------------------------
// Fused agg_l + gemm_{l+1} for SMALL layers (LDS < 27KB).
// ---------------------------------------------------------------------------
template<int DIN, int NOUT>
__global__ __launch_bounds__(THREADS)
void fused_agg_gemm_kernel(const short* __restrict__ tq_in, const float* __restrict__ qs_in,
                           const int* __restrict__ row_ptr, const int* __restrict__ col,
                           const float* __restrict__ norm_dst, const float* __restrict__ bias,
                           const short* __restrict__ wt_hi, const short* __restrict__ wt_lo,
                           const float* __restrict__ norm_src,
                           short* __restrict__ tq_out, float* __restrict__ qs_out, int N) {
    constexpr int Kp   = (DIN + 31) & ~31;
    constexpr int STR  = Kp + 8;
    constexpr int DINP = DIN + 4;
    constexpr int TPN  = DIN / 8;

    __shared__ float As[64 * DINP];
    __shared__ short lh[NOUT * STR];
    __shared__ short ll[NOUT * STR];

    const int tid = threadIdx.x;
    {
        constexpr int CNT = NOUT * STR / 2;
        const int* gh = (const int*)wt_hi;
        const int* gl = (const int*)wt_lo;
        int* sh = (int*)lh;
        int* sl = (int*)ll;
        for (int i = tid; i < CNT; i += THREADS) { sh[i] = gh[i]; sl[i] = gl[i]; }
    }

    const int ln = tid % TPN;
    for (int n0 = tid / TPN; n0 < 64; n0 += THREADS / TPN) {
        const int node = blockIdx.x * 64 + n0;
        if (node < N) {
            const int beg = row_ptr[node];
            const int end = row_ptr[node + 1];
            float acc[8];
#pragma unroll
            for (int c = 0; c < 8; ++c) acc[c] = 0.f;
            int j = beg;
            for (; j + 3 < end; j += 4) {
                int s0 = col[j], s1 = col[j + 1], s2 = col[j + 2], s3 = col[j + 3];
                short8_t v0 = *(const short8_t*)&tq_in[(size_t)s0 * DIN + ln * 8];
                short8_t v1 = *(const short8_t*)&tq_in[(size_t)s1 * DIN + ln * 8];
                short8_t v2 = *(const short8_t*)&tq_in[(size_t)s2 * DIN + ln * 8];
                short8_t v3 = *(const short8_t*)&tq_in[(size_t)s3 * DIN + ln * 8];
                float c0 = qs_in[s0], c1 = qs_in[s1], c2 = qs_in[s2], c3 = qs_in[s3];
#pragma unroll
                for (int c = 0; c < 8; ++c)
                    acc[c] += (float)v0[c] * c0 + (float)v1[c] * c1
                            + (float)v2[c] * c2 + (float)v3[c] * c3;
            }
            for (; j < end; ++j) {
                int s0 = col[j];
                short8_t v0 = *(const short8_t*)&tq_in[(size_t)s0 * DIN + ln * 8];
                float c0 = qs_in[s0];
#pragma unroll
                for (int c = 0; c < 8; ++c) acc[c] += (float)v0[c] * c0;
            }
            float nd = norm_dst[node];
#pragma unroll
            for (int c = 0; c < 8; ++c)
                As[n0 * DINP + ln * 8 + c] = fmaxf(acc[c] * nd + bias[ln * 8 + c], 0.f);
        }
    }
    __syncthreads();

    gemm_core_lds<DIN, NOUT, DINP>(As, lh, ll, norm_src, tq_out, qs_out, N, blockIdx.x, tid);
}

extern "C" void kernel_launch(void* const* d_in, const int* in_sizes, int n_in,
                              void* d_out, int out_size, void* d_ws, size_t ws_size,
                              hipStream_t stream) {
    const float* x     = (const float*)d_in[0];
    const int*   edges = (const int*)d_in[1];
    const float* W1 = (const float*)d_in[2];  const float* b1 = (const float*)d_in[3];
    const float* W2 = (const float*)d_in[4];  const float* b2 = (const float*)d_in[5];
    const float* W3 = (const float*)d_in[6];  const float* b3 = (const float*)d_in[7];
    const float* W4 = (const float*)d_in[8];  const float* b4 = (const float*)d_in[9];
    const float* W5 = (const float*)d_in[10]; const float* b5 = (const float*)d_in[11];

    const int N = in_sizes[0] / 128;   // 50000
    const int E = in_sizes[1] / 2;     // 800000
    const int* src = edges;
    const int* dst = edges + E;

    // ---- carve workspace ----
    char* ws = (char*)d_ws;
    size_t off = 0;
    auto carve = [&](size_t bytes) -> void* {
        void* p = ws + off;
        off += (bytes + 255) & ~(size_t)255;
        return p;
    };
    short* tqA      = (short*)carve((size_t)N * 128 * 2);   // L1 out (128) / L2 out (64) / L4 out (16)
    short* tqB      = (short*)carve((size_t)N * 64 * 2);    // L3 out (32) / L5 out (16)
    short* tqH      = (short*)carve((size_t)N * 128 * 2);   // agg1 out (int16, 128)
    float* norm_src = (float*)carve((size_t)N * 4);
    float* norm_dst = (float*)carve((size_t)N * 4);
    int*   row_ptr  = (int*)carve((size_t)(N + 1) * 4);
    int*   col      = (int*)carve((size_t)E * 4);
    float* qsA      = (float*)carve((size_t)2 * N * 4);     // L1 per-half; stride-1 reuse
    float* qsB      = (float*)carve((size_t)N * 4);
    float* qsH      = (float*)carve((size_t)N * 4);         // agg1 per-node scale
    int*   flags    = (int*)carve((size_t)256 * 4);
    short* wts      = (short*)carve((size_t)24576 * 2);
    unsigned* p_src = (unsigned*)carve((size_t)HIST_B * HWORDS * 4);   // 6.4 MB
    unsigned* p_dst = (unsigned*)carve((size_t)HIST_B * HWORDS * 4);   // 6.4 MB
    unsigned char* rank = (unsigned char*)carve((size_t)E);            // 0.8 MB
    (void)ws_size;

    short* w2h = wts;            short* w2l = w2h + 8704;
    short* w3h = w2l + 8704;     short* w3l = w3h + 2304;
    short* w4h = w3l + 2304;     short* w4l = w4h + 640;
    short* w5h = w4l + 640;      short* w5l = w5h + 640;   // end 24576

    const int chunk = (E + HIST_B - 1) / HIST_B;   // 6250
    const int gridG = (N + 63) / 64;               // 782

    // 1) packed front: gemm1 (both halves) || hist || W2-5 split + flag zero
    packed0_kernel<<<G1BLKS + 2 * HIST_B + 49, THREADS, 0, stream>>>(
        x, W1, W2, W3, W4, W5, tqA, qsA, src, dst, p_src, p_dst, rank, flags,
        w2h, w2l, w3h, w3l, w4h, w4l, w5h, w5l, E, chunk, N);

    // 2) reduce + full scan (4-way chunk split + lookback)
    reduce_scan_kernel<<<RS_BLOCKS, THREADS, 0, stream>>>(
        p_src, p_dst, norm_src, norm_dst, qsA, row_ptr, flags, N);

    // 3) scatter -> col (512 quarter-chunk blocks)
    scatter_kernel<<<4 * HIST_B, THREADS, 0, stream>>>(src, dst, rank, row_ptr, p_dst, col, E, chunk);

    // 4) agg1: edge-parallel x4, int16+scale output
    agg1_q_kernel<<<(N + 3) / 4, THREADS, 0, stream>>>(
        tqA, qsA, row_ptr, col, norm_dst, b1, tqH, qsH, N);

    // 5) gemm2: int16 A, row scale folded
    gemm_mfma_q_kernel<128, 64><<<gridG, THREADS, 0, stream>>>(
        tqH, qsH, w2h, w2l, norm_src, tqA, qsA, N);

    // 6-8) fused small layers
    fused_agg_gemm_kernel<64, 32><<<gridG, THREADS, 0, stream>>>(
        tqA, qsA, row_ptr, col, norm_dst, b2, w3h, w3l, norm_src, tqB, qsB, N);
    fused_agg_gemm_kernel<32, 16><<<gridG, THREADS, 0, stream>>>(
        tqB, qsB, row_ptr, col, norm_dst, b3, w4h, w4l, norm_src, tqA, qsA, N);
    fused_agg_gemm_kernel<16, 16><<<gridG, THREADS, 0, stream>>>(
        tqA, qsA, row_ptr, col, norm_dst, b4, w5h, w5l, norm_src, tqB, qsB, N);

    // 9) final aggregate -> d_out
    agg_q_kernel<16><<<(N + 127) / 128, THREADS, 0, stream>>>(
        tqB, qsB, row_ptr, col, norm_dst, b5, (float*)d_out, N);
}